// Round 11
// baseline (1807.598 us; speedup 1.0000x reference)
//
#include <hip/hip_runtime.h>
#include <cstdint>

typedef __attribute__((ext_vector_type(8))) short bf16x8;
typedef __attribute__((ext_vector_type(4))) float f32x4;
typedef unsigned short u16;
typedef unsigned long long u64;

// ---------- bf16 helpers (round-to-nearest-even) ----------
__device__ __forceinline__ u16 f2bf(float x) {
  unsigned u = __builtin_bit_cast(unsigned, x);
  return (u16)((u + 0x7FFFu + ((u >> 16) & 1u)) >> 16);
}
__device__ __forceinline__ float bf2f(u16 h) {
  unsigned u = ((unsigned)h) << 16;
  return __builtin_bit_cast(float, u);
}
__device__ __forceinline__ f32x4 mfma16(bf16x8 a, bf16x8 b, f32x4 c) {
  return __builtin_amdgcn_mfma_f32_16x16x32_bf16(a, b, c, 0, 0, 0);
}

// Coherent h exchange (validated r6): relaxed agent-scope atomics.
__device__ __forceinline__ bf16x8 ld_coh8(const u16* p) {
  u64 a = __hip_atomic_load((const u64*)p, __ATOMIC_RELAXED, __HIP_MEMORY_SCOPE_AGENT);
  u64 b = __hip_atomic_load((const u64*)(p + 4), __ATOMIC_RELAXED, __HIP_MEMORY_SCOPE_AGENT);
  ulonglong2 t;
  t.x = a;
  t.y = b;
  return __builtin_bit_cast(bf16x8, t);
}
__device__ __forceinline__ void st_coh16(u16* p, uint4 v) {
  ulonglong2 t = __builtin_bit_cast(ulonglong2, v);
  __hip_atomic_store((u64*)p, t.x, __ATOMIC_RELAXED, __HIP_MEMORY_SCOPE_AGENT);
  __hip_atomic_store((u64*)(p + 4), t.y, __ATOMIC_RELAXED, __HIP_MEMORY_SCOPE_AGENT);
}

// Packed MFMA-fragment index for Mat[r][k]: frag=(r>>4)*KC+(k>>5), lane=((k&31)>>3)<<4|(r&15), j=k&7
__device__ __forceinline__ size_t pidx(int r, int k, int KC) {
  return ((size_t)((r >> 4) * KC + (k >> 5))) * 512 +
         (size_t)(((((k & 31) >> 3) << 4) | (r & 15)) * 8) + (size_t)(k & 7);
}
// plane-triple interleaved gate row: orig (p, e) -> ((e>>4)*3+p)*16 + (e&15)
__device__ __forceinline__ int rowperm(int p, int e) {
  return (((e >> 4) * 3 + p) << 4) + (e & 15);
}

// ---------- setup kernels ----------
__global__ void k_round(const float* __restrict__ whh, const float* __restrict__ wun,
                        u16* __restrict__ whhp, u16* __restrict__ wunp) {
  int i = blockIdx.x * 256 + threadIdx.x, st = 1024 * 256;
  for (int j = i; j < 3072 * 1024; j += st) {
    int r = j >> 10, k = j & 1023;
    int p = r >> 10, e = r & 1023;
    whhp[pidx(rowperm(p, e), k, 32)] = f2bf(whh[j]);
  }
  for (int j = i; j < 256 * 1024; j += st) {
    int r = j >> 10, k = j & 1023;
    wunp[pidx(r, k, 32)] = f2bf(wun[j]);
  }
}

__global__ void k_hinit(const float* __restrict__ c, u16* __restrict__ hhi,
                        u16* __restrict__ hlo) {
  int i = blockIdx.x * 256 + threadIdx.x;  // 262144
  int b = i >> 10, e = i & 1023;
  float v = c[i];
  u16 hi = f2bf(v);
  size_t o = pidx(b, e, 32);
  hhi[o] = hi;
  hlo[o] = f2bf(v - bf2f(hi));
}

__global__ void k_zero(unsigned* __restrict__ bar) { bar[threadIdx.x] = 0u; }

// W_comb = W_ih @ W_tok -> packed bf16 frags (KC=8), plane-interleaved rows
__global__ void k_wcomb(const float* __restrict__ wih, const float* __restrict__ wtok,
                        u16* __restrict__ wcb) {
  __shared__ float la[64][33];
  __shared__ float lb[32][65];
  int i0 = blockIdx.x << 6, j0 = blockIdx.y << 6;
  int tid = threadIdx.x;
  int ty = tid >> 4, tx = tid & 15;
  float acc[4][4] = {};
  for (int k0 = 0; k0 < 1024; k0 += 32) {
    __syncthreads();
#pragma unroll
    for (int i = 0; i < 8; ++i) {
      int r = (tid >> 5) + i * 8, cc = tid & 31;
      la[r][cc] = wih[(size_t)(i0 + r) * 1024 + k0 + cc];
    }
#pragma unroll
    for (int i = 0; i < 8; ++i) {
      int idx = i * 256 + tid;
      int r = idx >> 6, cc = idx & 63;
      lb[r][cc] = wtok[(size_t)(k0 + r) * 256 + j0 + cc];
    }
    __syncthreads();
#pragma unroll
    for (int kk = 0; kk < 32; ++kk) {
      float av[4], bv[4];
#pragma unroll
      for (int ii = 0; ii < 4; ++ii) av[ii] = la[ty * 4 + ii][kk];
#pragma unroll
      for (int jj = 0; jj < 4; ++jj) bv[jj] = lb[kk][tx * 4 + jj];
#pragma unroll
      for (int ii = 0; ii < 4; ++ii)
#pragma unroll
        for (int jj = 0; jj < 4; ++jj) acc[ii][jj] += av[ii] * bv[jj];
    }
  }
#pragma unroll
  for (int ii = 0; ii < 4; ++ii)
#pragma unroll
    for (int jj = 0; jj < 4; ++jj) {
      int r = i0 + ty * 4 + ii;
      int p = r >> 10, e = r & 1023;
      wcb[pidx(rowperm(p, e), j0 + tx * 4 + jj, 8)] = f2bf(acc[ii][jj]);
    }
}

__global__ void k_bcomb(const float* __restrict__ wih, const float* __restrict__ btok,
                        const float* __restrict__ bih, float* __restrict__ bc) {
  __shared__ float red[256];
  int j = blockIdx.x, t = threadIdx.x;
  float s = 0.f;
  for (int e = t; e < 1024; e += 256) s += wih[(size_t)j * 1024 + e] * btok[e];
  red[t] = s;
  __syncthreads();
  for (int off = 128; off > 0; off >>= 1) {
    if (t < off) red[t] += red[t + off];
    __syncthreads();
  }
  if (t == 0) bc[j] = red[0] + bih[j];
}

// x packed per step-slice (KC=8): slice k holds x[:, :, 127+k] for k in [1,128)
__global__ void k_xprep(const float* __restrict__ x, u16* __restrict__ xhi,
                        u16* __restrict__ xlo) {
  __shared__ float t[64][129];
  int bid = blockIdx.x;
  int b = bid >> 2, d0 = (bid & 3) << 6;
  int tid = threadIdx.x;
#pragma unroll
  for (int i = 0; i < 32; ++i) {
    int idx = i * 256 + tid;
    int dd = idx >> 7, tt = idx & 127;
    t[dd][tt] = x[(size_t)b * 65536 + (size_t)(d0 + dd) * 256 + 128 + tt];
  }
  __syncthreads();
#pragma unroll
  for (int i = 0; i < 32; ++i) {
    int idx = i * 256 + tid;
    int dd = idx & 63, kk = idx >> 6;
    if (kk < 127) {
      float v = t[dd][kk];
      u16 hi = f2bf(v);
      size_t o = (size_t)(kk + 1) * 65536 + pidx(b, d0 + dd, 8);
      xhi[o] = hi;
      xlo[o] = f2bf(v - bf2f(hi));
    }
  }
}

// ---------- persistent recurrence: wide-E decomposition (S=16), W from L2, h LDS-staged ----------
// 256 WGs x 512 thr. WG (es=bid&15, g=bid>>4): rows [g*16,+16), e-cols [es*64,+64) all planes.
// XCD(bid)=bid%8 => e-slice es on XCD es%8: W slice (2 es x 384KB) stays L2-resident.
// h exchange: relaxed agent atomics (no cache maintenance); staged once per WG into LDS.
__launch_bounds__(512, 1)
__global__ void k_gru4(u16* __restrict__ hhi, u16* __restrict__ hlo,
                       const u16* __restrict__ xhi, const u16* __restrict__ xlo,
                       const u16* __restrict__ whp, const u16* __restrict__ wcp,
                       const float* __restrict__ bih, const float* __restrict__ bcb,
                       const float* __restrict__ bhh, u16* __restrict__ ys,
                       unsigned* __restrict__ bar) {
  __shared__ __align__(16) u16 lhh[32][512];      // 32KB staged h hi (frag-major)
  __shared__ __align__(16) u16 lhl[32][512];      // 32KB staged h lo
  __shared__ __align__(16) float red[4][4][256];  // 16KB [eb4][gate][frag f32]
  __shared__ __align__(16) u16 sth[16][64];       // 2KB
  __shared__ __align__(16) u16 stl[16][64];       // 2KB

  int bid = blockIdx.x;
  int es = bid & 15;  // e-slice (64 cols); XCD = es%8 (round-robin heuristic)
  int g = bid >> 4;   // row group (16 rows), 16 groups
  int tid = threadIdx.x;
  int w = tid >> 6, lane = tid & 63, l15 = lane & 15, l4 = lane >> 4;
  int eb4 = w & 3, ws = w >> 2;  // wave = (e 16-block, K-half)
  int eb16 = es * 4 + eb4;

  // per-thread bias constants for epilogue (col e)
  int e = es * 64 + eb4 * 16 + l15;
  float bhr = bhh[e], bhz = bhh[1024 + e], bhn = bhh[2048 + e];
  float bAr = bih[e] + bhr, bAz = bih[1024 + e] + bhz, bAn = bih[2048 + e];
  float bBr = bcb[e] + bhr, bBz = bcb[1024 + e] + bhz, bBn = bcb[2048 + e];

  unsigned* cnt_p = bar + g * 16;
  unsigned* gen_p = bar + g * 16 + 8;

  // W pointers (global, L2-resident per XCD)
  const u16* Bp0 = whp + ((size_t)((eb16 * 3 + 0) * 32)) * 512 + (size_t)(lane * 8);
  const u16* Bp1 = whp + ((size_t)((eb16 * 3 + 1) * 32)) * 512 + (size_t)(lane * 8);
  const u16* Bp2 = whp + ((size_t)((eb16 * 3 + 2) * 32)) * 512 + (size_t)(lane * 8);
  const u16* Cp0 = wcp + ((size_t)((eb16 * 3 + 0) * 8)) * 512 + (size_t)(lane * 8);
  const u16* Cp1 = wcp + ((size_t)((eb16 * 3 + 1) * 8)) * 512 + (size_t)(lane * 8);
  const u16* Cp2 = wcp + ((size_t)((eb16 * 3 + 2) * 8)) * 512 + (size_t)(lane * 8);

  for (int k = 0; k < 128; ++k) {
    int cur = k & 1, nxt = cur ^ 1;

    f32x4 aRh{}, aRl{}, aZh{}, aZl{}, aNh{}, aNl{}, aXh{}, aXl{};

    // ---- x-part FIRST (no h dependency): overlaps barrier wait. All from L2. ----
    if (k > 0) {
      const u16* Xh = xhi + (size_t)k * 65536 + ((size_t)(g * 8)) * 512 + (size_t)(lane * 8);
      const u16* Xl = xlo + (size_t)k * 65536 + ((size_t)(g * 8)) * 512 + (size_t)(lane * 8);
#pragma unroll
      for (int kc = 0; kc < 4; ++kc) {
        int kk = ws * 4 + kc;
        bf16x8 ah = *(const bf16x8*)(Xh + (size_t)kk * 512);
        bf16x8 al = *(const bf16x8*)(Xl + (size_t)kk * 512);
        bf16x8 b0 = *(const bf16x8*)(Cp0 + (size_t)kk * 512);
        bf16x8 b1 = *(const bf16x8*)(Cp1 + (size_t)kk * 512);
        bf16x8 b2 = *(const bf16x8*)(Cp2 + (size_t)kk * 512);
        aRh = mfma16(ah, b0, aRh); aRl = mfma16(al, b0, aRl);
        aZh = mfma16(ah, b1, aZh); aZl = mfma16(al, b1, aZl);
        aXh = mfma16(ah, b2, aXh); aXl = mfma16(al, b2, aXl);
      }
      // ---- group barrier wait (16 WGs): relaxed spin only ----
      if (tid == 0) {
        while (__hip_atomic_load(gen_p, __ATOMIC_RELAXED, __HIP_MEMORY_SCOPE_AGENT) <
               (unsigned)k) {
          __builtin_amdgcn_s_sleep(2);
        }
      }
      __syncthreads();
    }

    // ---- stage h (16 rows, full K) into LDS: wave w loads frags w*4..w*4+3 ----
    {
      const u16* Hh = hhi + (size_t)cur * 262144 + ((size_t)(g * 32)) * 512 + (size_t)(lane * 8);
      const u16* Hl = hlo + (size_t)cur * 262144 + ((size_t)(g * 32)) * 512 + (size_t)(lane * 8);
      bf16x8 vh[4], vl[4];
#pragma unroll
      for (int i = 0; i < 4; ++i) {
        int kk = w * 4 + i;
        vh[i] = ld_coh8(Hh + (size_t)kk * 512);
        vl[i] = ld_coh8(Hl + (size_t)kk * 512);
      }
#pragma unroll
      for (int i = 0; i < 4; ++i) {
        int kk = w * 4 + i;
        *(bf16x8*)&lhh[kk][lane * 8] = vh[i];
        *(bf16x8*)&lhl[kk][lane * 8] = vl[i];
      }
    }
    __syncthreads();

    // ---- h-part: A from LDS, B (W_hh) streamed from L2 ----
#pragma unroll
    for (int kc = 0; kc < 16; ++kc) {
      int kk = ws * 16 + kc;
      bf16x8 ah = *(const bf16x8*)&lhh[kk][lane * 8];
      bf16x8 al = *(const bf16x8*)&lhl[kk][lane * 8];
      bf16x8 b0 = *(const bf16x8*)(Bp0 + (size_t)kk * 512);
      bf16x8 b1 = *(const bf16x8*)(Bp1 + (size_t)kk * 512);
      bf16x8 b2 = *(const bf16x8*)(Bp2 + (size_t)kk * 512);
      aRh = mfma16(ah, b0, aRh); aRl = mfma16(al, b0, aRl);
      aZh = mfma16(ah, b1, aZh); aZl = mfma16(al, b1, aZl);
      aNh = mfma16(ah, b2, aNh); aNl = mfma16(al, b2, aNl);
    }

    // ---- 2-way K-split reduction ----
    if (ws == 1) {
      *(f32x4*)&red[eb4][0][lane * 4] = aRh + aRl;
      *(f32x4*)&red[eb4][1][lane * 4] = aZh + aZl;
      *(f32x4*)&red[eb4][2][lane * 4] = aNh + aNl;
      *(f32x4*)&red[eb4][3][lane * 4] = aXh + aXl;
    }
    __syncthreads();
    if (ws == 0) {
      f32x4 vR = aRh + aRl + *(const f32x4*)&red[eb4][0][lane * 4];
      f32x4 vZ = aZh + aZl + *(const f32x4*)&red[eb4][1][lane * 4];
      f32x4 vN = aNh + aNl + *(const f32x4*)&red[eb4][2][lane * 4];
      f32x4 vX = aXh + aXl + *(const f32x4*)&red[eb4][3][lane * 4];
      float bir = k ? bBr : bAr, biz = k ? bBz : bAz, bin = k ? bBn : bAn;
      int e64 = eb4 * 16 + l15;
      int kcs = es * 2 + (e64 >> 5);  // FIX r10: staged-LDS chunk of e_global = es*64+e64
      int lif_base = ((e64 & 31) >> 3) << 4;
      int elem = l15 & 7;
#pragma unroll
      for (int j = 0; j < 4; ++j) {
        int row_rel = l4 * 4 + j;  // 0..15
        int lif = lif_base | row_rel;
        float hold = bf2f(lhh[kcs][lif * 8 + elem]) + bf2f(lhl[kcs][lif * 8 + elem]);
        float gr = vR[j] + bir;
        float gz = vZ[j] + biz;
        float gh = vN[j] + bhn;
        float gx = vX[j] + bin;
        float r = 1.f / (1.f + __expf(-gr));
        float z = 1.f / (1.f + __expf(-gz));
        float n = 1.f - 2.f / (1.f + __expf(2.f * (gx + r * gh)));
        float h = (1.f - z) * n + z * hold;
        u16 hi = f2bf(h);
        sth[row_rel][e64] = hi;
        stl[row_rel][e64] = f2bf(h - bf2f(hi));
      }
    }
    __syncthreads();

    // ---- stores: h chunk (2 frags hi + 2 lo, write-through), ys (plain) ----
    if (tid < 256) {
      int c = tid & 63, part = tid >> 6;
      int t = part & 1, isLo = part >> 1;
      int r15 = c & 15, oct = c >> 4;
      const u16* src = isLo ? &stl[r15][t * 32 + oct * 8] : &sth[r15][t * 32 + oct * 8];
      size_t f = (size_t)(g * 32 + es * 2 + t);
      u16* dst = (isLo ? hlo : hhi) + (size_t)nxt * 262144 + f * 512 + (size_t)(c * 8);
      st_coh16(dst, *(const uint4*)src);
    } else if (tid < 384) {
      int c = tid - 256;
      int b_rel = c >> 3, t = (c >> 2) & 1, oct = c & 3;
      size_t f = ((size_t)((g * 16 + b_rel) * 8 + (k >> 4))) * 32 + (size_t)(es * 2 + t);
      *(uint4*)(ys + f * 512 + (size_t)(((oct << 4) | (k & 15)) * 8)) =
          *(const uint4*)&sth[b_rel][t * 32 + oct * 8];
    }

    if (k < 127) {
      // drain stores (syncthreads waits vmcnt(0) before s_barrier), then relaxed arrive
      __syncthreads();
      if (tid == 0) {
        unsigned t = __hip_atomic_fetch_add(cnt_p, 1u, __ATOMIC_RELAXED,
                                            __HIP_MEMORY_SCOPE_AGENT);
        if (t == (unsigned)(k + 1) * 16u - 1u)
          __hip_atomic_store(gen_p, (unsigned)(k + 1), __ATOMIC_RELAXED,
                             __HIP_MEMORY_SCOPE_AGENT);
      }
    }
  }
}

// ---------- untokenizer: packed frags, direct full-line float4 stores, no big LDS ----------
__launch_bounds__(256, 4)
__global__ void k_untok3(const u16* __restrict__ ysp, const u16* __restrict__ wunp,
                         const float* __restrict__ bun, float* __restrict__ out) {
  int bid = blockIdx.x;  // 1024 = 512 mtiles x 2 d-halves
  int mtile = bid >> 1, dh = bid & 1;
  int b = mtile >> 1, kk0 = (mtile & 1) << 6;
  int w = threadIdx.x >> 6, lane = threadIdx.x & 63, l15 = lane & 15, l4 = lane >> 4;
  int rg = mtile * 4 + w;
  const u16* A = ysp + (size_t)rg * 16384 + (size_t)(lane * 8);
  f32x4 acc[8] = {};
  float bv[8];
#pragma unroll
  for (int nt = 0; nt < 8; ++nt) bv[nt] = bun[dh * 128 + nt * 16 + l15];
#pragma unroll 4
  for (int kc = 0; kc < 32; ++kc) {
    bf16x8 a = *(const bf16x8*)(A + (size_t)kc * 512);
#pragma unroll
    for (int nt = 0; nt < 8; ++nt) {
      const u16* B = wunp + ((size_t)((dh * 8 + nt) * 32 + kc)) * 512 + (size_t)(lane * 8);
      acc[nt] = mfma16(a, *(const bf16x8*)B, acc[nt]);
    }
  }
#pragma unroll
  for (int nt = 0; nt < 8; ++nt) {
    float4 v = {acc[nt][0] + bv[nt], acc[nt][1] + bv[nt], acc[nt][2] + bv[nt],
                acc[nt][3] + bv[nt]};
    int d = dh * 128 + nt * 16 + l15;
    *(float4*)(out + (size_t)b * 32768 + (size_t)d * 128 + kk0 + w * 16 + l4 * 4) = v;
  }
}

// ---------- launch ----------
extern "C" void kernel_launch(void* const* d_in, const int* in_sizes, int n_in,
                              void* d_out, int out_size, void* d_ws, size_t ws_size,
                              hipStream_t stream) {
  const float* c_in = (const float*)d_in[0];
  const float* x_in = (const float*)d_in[2];
  const float* Wih  = (const float*)d_in[3];
  const float* Whh  = (const float*)d_in[4];
  const float* bih  = (const float*)d_in[5];
  const float* bhh  = (const float*)d_in[6];
  const float* Wtok = (const float*)d_in[7];
  const float* btok = (const float*)d_in[8];
  const float* Wun  = (const float*)d_in[9];
  const float* bun  = (const float*)d_in[10];
  float* out = (float*)d_out;
  char* ws = (char*)d_ws;

  const size_t OW_HH = 0;                     // u16 packed [6144 frags][512]
  const size_t OW_C  = 6291456;               // u16 packed [1536 frags][512]
  const size_t OW_UN = 7864320;               // u16 packed [512 frags][512]
  const size_t OBC   = 8388608;               // f32 [3072]
  const size_t OXHI  = 8400896;               // u16 [128][65536]
  const size_t OXLO  = 25178112;
  const size_t OHHI  = 41955328;              // u16 [2][262144]
  const size_t OHLO  = 43003904;
  const size_t OYS   = 44052480;              // u16 packed [65536 frags][512]
  const size_t OBAR  = 111161344;             // u32 [256] barrier state
  const size_t NEED  = 111162368;
  if (ws_size < NEED) return;

  u16* whh_p = (u16*)(ws + OW_HH);
  u16* wc_p  = (u16*)(ws + OW_C);
  u16* wun_p = (u16*)(ws + OW_UN);
  float* bc  = (float*)(ws + OBC);
  u16* xhi   = (u16*)(ws + OXHI);
  u16* xlo   = (u16*)(ws + OXLO);
  u16* hhi   = (u16*)(ws + OHHI);
  u16* hlo   = (u16*)(ws + OHLO);
  u16* ys    = (u16*)(ws + OYS);
  unsigned* bar = (unsigned*)(ws + OBAR);

  k_round<<<1024, 256, 0, stream>>>(Whh, Wun, whh_p, wun_p);
  k_wcomb<<<dim3(48, 4), 256, 0, stream>>>(Wih, Wtok, wc_p);
  k_bcomb<<<3072, 256, 0, stream>>>(Wih, btok, bih, bc);
  k_xprep<<<1024, 256, 0, stream>>>(x_in, xhi, xlo);
  k_hinit<<<1024, 256, 0, stream>>>(c_in, hhi, hlo);
  k_zero<<<1, 256, 0, stream>>>(bar);

  {
    u16* hhi_l = hhi;
    u16* hlo_l = hlo;
    const u16* xhi_l = xhi;
    const u16* xlo_l = xlo;
    const u16* whp_l = whh_p;
    const u16* wcp_l = wc_p;
    const float* bih_l = bih;
    const float* bc_l = bc;
    const float* bhh_l = bhh;
    u16* ys_l = ys;
    unsigned* bar_l = bar;
    void* args[] = {&hhi_l, &hlo_l, &xhi_l, &xlo_l, &whp_l, &wcp_l,
                    &bih_l, &bc_l, &bhh_l, &ys_l, &bar_l};
    hipLaunchCooperativeKernel((const void*)k_gru4, dim3(256), dim3(512), args, 0, stream);
  }

  k_untok3<<<1024, 256, 0, stream>>>(ys, wun_p, bun, out);
}

// Round 12
// 1216.916 us; speedup vs baseline: 1.4854x; 1.4854x over previous
//
#include <hip/hip_runtime.h>
#include <cstdint>

typedef __attribute__((ext_vector_type(8))) short bf16x8;
typedef __attribute__((ext_vector_type(4))) float f32x4;
typedef unsigned short u16;
typedef unsigned long long u64;

// ---------- bf16 helpers (round-to-nearest-even) ----------
__device__ __forceinline__ u16 f2bf(float x) {
  unsigned u = __builtin_bit_cast(unsigned, x);
  return (u16)((u + 0x7FFFu + ((u >> 16) & 1u)) >> 16);
}
__device__ __forceinline__ float bf2f(u16 h) {
  unsigned u = ((unsigned)h) << 16;
  return __builtin_bit_cast(float, u);
}
__device__ __forceinline__ f32x4 mfma16(bf16x8 a, bf16x8 b, f32x4 c) {
  return __builtin_amdgcn_mfma_f32_16x16x32_bf16(a, b, c, 0, 0, 0);
}

// Coherent h exchange (validated r6): relaxed agent-scope atomics.
__device__ __forceinline__ bf16x8 ld_coh8(const u16* p) {
  u64 a = __hip_atomic_load((const u64*)p, __ATOMIC_RELAXED, __HIP_MEMORY_SCOPE_AGENT);
  u64 b = __hip_atomic_load((const u64*)(p + 4), __ATOMIC_RELAXED, __HIP_MEMORY_SCOPE_AGENT);
  ulonglong2 t;
  t.x = a;
  t.y = b;
  return __builtin_bit_cast(bf16x8, t);
}
__device__ __forceinline__ void st_coh16(u16* p, uint4 v) {
  ulonglong2 t = __builtin_bit_cast(ulonglong2, v);
  __hip_atomic_store((u64*)p, t.x, __ATOMIC_RELAXED, __HIP_MEMORY_SCOPE_AGENT);
  __hip_atomic_store((u64*)(p + 4), t.y, __ATOMIC_RELAXED, __HIP_MEMORY_SCOPE_AGENT);
}

// Packed MFMA-fragment index for Mat[r][k]: frag=(r>>4)*KC+(k>>5), lane=((k&31)>>3)<<4|(r&15), j=k&7
__device__ __forceinline__ size_t pidx(int r, int k, int KC) {
  return ((size_t)((r >> 4) * KC + (k >> 5))) * 512 +
         (size_t)(((((k & 31) >> 3) << 4) | (r & 15)) * 8) + (size_t)(k & 7);
}
// plane-triple interleaved gate row: orig (p, e) -> ((e>>4)*3+p)*16 + (e&15)
__device__ __forceinline__ int rowperm(int p, int e) {
  return (((e >> 4) * 3 + p) << 4) + (e & 15);
}

// ---------- setup kernels ----------
__global__ void k_round(const float* __restrict__ whh, const float* __restrict__ wun,
                        u16* __restrict__ whhp, u16* __restrict__ wunp) {
  int i = blockIdx.x * 256 + threadIdx.x, st = 1024 * 256;
  for (int j = i; j < 3072 * 1024; j += st) {
    int r = j >> 10, k = j & 1023;
    int p = r >> 10, e = r & 1023;
    whhp[pidx(rowperm(p, e), k, 32)] = f2bf(whh[j]);
  }
  for (int j = i; j < 256 * 1024; j += st) {
    int r = j >> 10, k = j & 1023;
    wunp[pidx(r, k, 32)] = f2bf(wun[j]);
  }
}

__global__ void k_hinit(const float* __restrict__ c, u16* __restrict__ hhi,
                        u16* __restrict__ hlo) {
  int i = blockIdx.x * 256 + threadIdx.x;  // 262144
  int b = i >> 10, e = i & 1023;
  float v = c[i];
  u16 hi = f2bf(v);
  size_t o = pidx(b, e, 32);
  hhi[o] = hi;
  hlo[o] = f2bf(v - bf2f(hi));
}

__global__ void k_zero(unsigned* __restrict__ bar) { bar[threadIdx.x] = 0u; }

// W_comb = W_ih @ W_tok -> packed bf16 frags (KC=8), plane-interleaved rows
__global__ void k_wcomb(const float* __restrict__ wih, const float* __restrict__ wtok,
                        u16* __restrict__ wcb) {
  __shared__ float la[64][33];
  __shared__ float lb[32][65];
  int i0 = blockIdx.x << 6, j0 = blockIdx.y << 6;
  int tid = threadIdx.x;
  int ty = tid >> 4, tx = tid & 15;
  float acc[4][4] = {};
  for (int k0 = 0; k0 < 1024; k0 += 32) {
    __syncthreads();
#pragma unroll
    for (int i = 0; i < 8; ++i) {
      int r = (tid >> 5) + i * 8, cc = tid & 31;
      la[r][cc] = wih[(size_t)(i0 + r) * 1024 + k0 + cc];
    }
#pragma unroll
    for (int i = 0; i < 8; ++i) {
      int idx = i * 256 + tid;
      int r = idx >> 6, cc = idx & 63;
      lb[r][cc] = wtok[(size_t)(k0 + r) * 256 + j0 + cc];
    }
    __syncthreads();
#pragma unroll
    for (int kk = 0; kk < 32; ++kk) {
      float av[4], bv[4];
#pragma unroll
      for (int ii = 0; ii < 4; ++ii) av[ii] = la[ty * 4 + ii][kk];
#pragma unroll
      for (int jj = 0; jj < 4; ++jj) bv[jj] = lb[kk][tx * 4 + jj];
#pragma unroll
      for (int ii = 0; ii < 4; ++ii)
#pragma unroll
        for (int jj = 0; jj < 4; ++jj) acc[ii][jj] += av[ii] * bv[jj];
    }
  }
#pragma unroll
  for (int ii = 0; ii < 4; ++ii)
#pragma unroll
    for (int jj = 0; jj < 4; ++jj) {
      int r = i0 + ty * 4 + ii;
      int p = r >> 10, e = r & 1023;
      wcb[pidx(rowperm(p, e), j0 + tx * 4 + jj, 8)] = f2bf(acc[ii][jj]);
    }
}

__global__ void k_bcomb(const float* __restrict__ wih, const float* __restrict__ btok,
                        const float* __restrict__ bih, float* __restrict__ bc) {
  __shared__ float red[256];
  int j = blockIdx.x, t = threadIdx.x;
  float s = 0.f;
  for (int e = t; e < 1024; e += 256) s += wih[(size_t)j * 1024 + e] * btok[e];
  red[t] = s;
  __syncthreads();
  for (int off = 128; off > 0; off >>= 1) {
    if (t < off) red[t] += red[t + off];
    __syncthreads();
  }
  if (t == 0) bc[j] = red[0] + bih[j];
}

// x packed per step-slice (KC=8): slice k holds x[:, :, 127+k] for k in [1,128)
__global__ void k_xprep(const float* __restrict__ x, u16* __restrict__ xhi,
                        u16* __restrict__ xlo) {
  __shared__ float t[64][129];
  int bid = blockIdx.x;
  int b = bid >> 2, d0 = (bid & 3) << 6;
  int tid = threadIdx.x;
#pragma unroll
  for (int i = 0; i < 32; ++i) {
    int idx = i * 256 + tid;
    int dd = idx >> 7, tt = idx & 127;
    t[dd][tt] = x[(size_t)b * 65536 + (size_t)(d0 + dd) * 256 + 128 + tt];
  }
  __syncthreads();
#pragma unroll
  for (int i = 0; i < 32; ++i) {
    int idx = i * 256 + tid;
    int dd = idx & 63, kk = idx >> 6;
    if (kk < 127) {
      float v = t[dd][kk];
      u16 hi = f2bf(v);
      size_t o = (size_t)(kk + 1) * 65536 + pidx(b, d0 + dd, 8);
      xhi[o] = hi;
      xlo[o] = f2bf(v - bf2f(hi));
    }
  }
}

// ---------- persistent recurrence: r6 structure, hi-only recurrent matmul ----------
// 256 WGs x 512 thr. Colocated decode (r8): group mt on XCD pair {2mt,2mt+1}.
// W LDS-resident. h exchange via relaxed agent atomics; matmul consumes h_hi ONLY
// (halves broadcast bytes + MFMA); h state stays hi+lo (hold stash reads both, local).
__launch_bounds__(512, 1)
__global__ void k_gru2(u16* __restrict__ hhi, u16* __restrict__ hlo,
                       const u16* __restrict__ xhi, const u16* __restrict__ xlo,
                       const u16* __restrict__ whp, const u16* __restrict__ wcp,
                       const float* __restrict__ bih, const float* __restrict__ bcb,
                       const float* __restrict__ bhh, u16* __restrict__ ys,
                       unsigned* __restrict__ bar) {
  __shared__ __align__(16) u16 lwh[3][32][512];   // 96KB
  __shared__ __align__(16) u16 lwc[3][8][512];    // 24KB
  __shared__ __align__(16) float red[4][4][256];  // 16KB
  __shared__ __align__(16) u16 sth[64][16];       // 2KB
  __shared__ __align__(16) u16 stl[64][16];       // 2KB
  __shared__ u16 hold_h[64][34];                  // 4.25KB
  __shared__ u16 hold_l[64][34];                  // 4.25KB

  int bid = blockIdx.x;
  // Co-location decode: XCD(bid)=bid%8 (heuristic) => group mt on XCDs {2mt, 2mt+1}.
  int mt = (bid >> 1) & 3;
  int eb = ((bid & 1) << 5) | (bid >> 3);
  int tid = threadIdx.x;
  int w = tid >> 6, lane = tid & 63, l15 = lane & 15, l4 = lane >> 4;
  int ws = w & 1, mw = w >> 1;
  int rg = mt * 4 + mw;  // 16-row frag group this wave handles

  // W slice -> LDS (plain loads; read-only data)
  for (int p = 0; p < 3; ++p) {
    const u16* s1 = whp + ((size_t)(eb * 3 + p) * 32) * 512;
#pragma unroll
    for (int i = 0; i < 4; ++i)
      *(uint4*)&lwh[p][0][i * 4096 + tid * 8] = *(const uint4*)(s1 + i * 4096 + tid * 8);
    const u16* s2 = wcp + ((size_t)(eb * 3 + p) * 8) * 512;
    *(uint4*)&lwc[p][0][tid * 8] = *(const uint4*)(s2 + tid * 8);
  }
  __syncthreads();

  int e = (eb << 4) + l15;
  float bhr = bhh[e], bhz = bhh[1024 + e], bhn = bhh[2048 + e];
  float bAr = bih[e] + bhr, bAz = bih[1024 + e] + bhz, bAn = bih[2048 + e];
  float bBr = bcb[e] + bhr, bBz = bcb[1024 + e] + bhz, bBn = bcb[2048 + e];

  unsigned* cnt_p = bar + mt * 64;
  unsigned* gen_p = bar + mt * 64 + 32;

  const size_t hrow = (size_t)rg * 16384 + (size_t)(lane * 8);  // rg*32*512
  const size_t xrow = (size_t)rg * 4096 + (size_t)(lane * 8);   // rg*8*512
  int hold_kc = eb >> 1;

  for (int k = 0; k < 128; ++k) {
    int cur = k & 1, nxt = cur ^ 1;

    // accumulator chains: 0/1 split for ILP (h: kc parity; x: hi chain0 / lo chain1)
    f32x4 aR0{}, aR1{}, aZ0{}, aZ1{}, aN0{}, aN1{}, aX0{}, aX1{};

    // ---- x-part FIRST (no h dependency): overlaps the barrier wait ----
    if (k > 0) {
      const u16* Xh = xhi + (size_t)k * 65536 + xrow;
      const u16* Xl = xlo + (size_t)k * 65536 + xrow;
#pragma unroll
      for (int kc = 0; kc < 4; ++kc) {
        int kk = ws * 4 + kc;
        bf16x8 ah = *(const bf16x8*)(Xh + (size_t)kk * 512);
        bf16x8 al = *(const bf16x8*)(Xl + (size_t)kk * 512);
        bf16x8 b0 = *(const bf16x8*)&lwc[0][kk][lane * 8];
        bf16x8 b1 = *(const bf16x8*)&lwc[1][kk][lane * 8];
        bf16x8 b2 = *(const bf16x8*)&lwc[2][kk][lane * 8];
        aR0 = mfma16(ah, b0, aR0); aR1 = mfma16(al, b0, aR1);
        aZ0 = mfma16(ah, b1, aZ0); aZ1 = mfma16(al, b1, aZ1);
        aX0 = mfma16(ah, b2, aX0); aX1 = mfma16(al, b2, aX1);
      }
      // ---- group barrier wait: relaxed spin only (no cache maintenance) ----
      if (tid == 0) {
        while (__hip_atomic_load(gen_p, __ATOMIC_RELAXED, __HIP_MEMORY_SCOPE_AGENT) <
               (unsigned)k) {
          __builtin_amdgcn_s_sleep(2);
        }
      }
      __syncthreads();
    }

    // ---- h-part: HI ONLY (coherent atomic loads; half the broadcast bytes) ----
    const u16* Hh = hhi + (size_t)cur * 262144 + hrow;
#pragma unroll
    for (int kc = 0; kc < 16; ++kc) {
      int kk = ws * 16 + kc;
      bf16x8 ah = ld_coh8(Hh + (size_t)kk * 512);
      bf16x8 b0 = *(const bf16x8*)&lwh[0][kk][lane * 8];
      bf16x8 b1 = *(const bf16x8*)&lwh[1][kk][lane * 8];
      bf16x8 b2 = *(const bf16x8*)&lwh[2][kk][lane * 8];
      f32x4& rr = (kc & 1) ? aR1 : aR0;
      f32x4& zz = (kc & 1) ? aZ1 : aZ0;
      f32x4& nn = (kc & 1) ? aN1 : aN0;
      rr = mfma16(ah, b0, rr);
      zz = mfma16(ah, b1, zz);
      nn = mfma16(ah, b2, nn);
    }

    // ---- hold stash: ws0 waves fetch the h_old frag (hi+lo) this WG needs ----
    if (ws == 0) {
      bf16x8 hh = ld_coh8(hhi + (size_t)cur * 262144 + (size_t)rg * 16384 +
                          (size_t)hold_kc * 512 + lane * 8);
      bf16x8 hl = ld_coh8(hlo + (size_t)cur * 262144 + (size_t)rg * 16384 +
                          (size_t)hold_kc * 512 + lane * 8);
      int r15 = lane & 15, oct = lane >> 4;
#pragma unroll
      for (int j = 0; j < 8; ++j) {
        hold_h[mw * 16 + r15][oct * 8 + j] = (u16)hh[j];
        hold_l[mw * 16 + r15][oct * 8 + j] = (u16)hl[j];
      }
    }

    if (ws == 1) {
      *(f32x4*)&red[mw][0][lane * 4] = aR0 + aR1;
      *(f32x4*)&red[mw][1][lane * 4] = aZ0 + aZ1;
      *(f32x4*)&red[mw][2][lane * 4] = aN0 + aN1;
      *(f32x4*)&red[mw][3][lane * 4] = aX0 + aX1;
    }
    __syncthreads();
    if (ws == 0) {
      f32x4 vR = aR0 + aR1 + *(const f32x4*)&red[mw][0][lane * 4];
      f32x4 vZ = aZ0 + aZ1 + *(const f32x4*)&red[mw][1][lane * 4];
      f32x4 vN = aN0 + aN1 + *(const f32x4*)&red[mw][2][lane * 4];
      f32x4 vX = aX0 + aX1 + *(const f32x4*)&red[mw][3][lane * 4];
      float bir = k ? bBr : bAr, biz = k ? bBz : bAz, bin = k ? bBn : bAn;
      int kwf = (eb & 1) * 16 + l15;
#pragma unroll
      for (int j = 0; j < 4; ++j) {
        int b15 = l4 * 4 + j;
        int row_rel = mw * 16 + b15;
        float hold = bf2f(hold_h[row_rel][kwf]) + bf2f(hold_l[row_rel][kwf]);
        float gr = vR[j] + bir;
        float gz = vZ[j] + biz;
        float gh = vN[j] + bhn;
        float gx = vX[j] + bin;
        float r = 1.f / (1.f + __expf(-gr));
        float z = 1.f / (1.f + __expf(-gz));
        float n = 1.f - 2.f / (1.f + __expf(2.f * (gx + r * gh)));
        float h = (1.f - z) * n + z * hold;
        u16 hi = f2bf(h);
        sth[row_rel][l15] = hi;
        stl[row_rel][l15] = f2bf(h - bf2f(hi));
      }
    }
    __syncthreads();

    // ---- stores: h (coherent write-through), ys (plain; consumed after kernel) ----
    if (tid < 256) {
      int c = tid & 127, row_rel = c >> 1, oct = c & 1;
      int frag = (mt * 4 + (row_rel >> 4)) * 32 + (eb >> 1);
      int inl = ((eb & 1) * 2 + oct) * 16 + (row_rel & 15);
      size_t off = (size_t)frag * 512 + (size_t)(inl * 8);
      uint4 v = (tid < 128) ? *(const uint4*)&sth[row_rel][oct * 8]
                            : *(const uint4*)&stl[row_rel][oct * 8];
      u16* dst = ((tid < 128) ? hhi : hlo) + (size_t)nxt * 262144;
      st_coh16(dst + off, v);
    } else if (tid < 384) {
      int c = tid - 256, row_rel = c >> 1, oct = c & 1;
      int b = mt * 64 + row_rel;
      size_t fragrg = (size_t)(b * 8 + (k >> 4));
      size_t off = (fragrg * 32 + (size_t)(eb >> 1)) * 512 +
                   (size_t)((((eb & 1) * 2 + oct) * 16 + (k & 15)) * 8);
      *(uint4*)(ys + off) = *(const uint4*)&sth[row_rel][oct * 8];
    }

    if (k < 127) {
      // drain stores (syncthreads waits vmcnt(0) before s_barrier), then relaxed arrive
      __syncthreads();
      if (tid == 0) {
        unsigned t = __hip_atomic_fetch_add(cnt_p, 1u, __ATOMIC_RELAXED,
                                            __HIP_MEMORY_SCOPE_AGENT);
        if (t == (unsigned)(k + 1) * 64u - 1u)
          __hip_atomic_store(gen_p, (unsigned)(k + 1), __ATOMIC_RELAXED,
                             __HIP_MEMORY_SCOPE_AGENT);
      }
    }
  }
}

// ---------- untokenizer: packed frags, direct full-line float4 stores, no big LDS ----------
__launch_bounds__(256, 4)
__global__ void k_untok3(const u16* __restrict__ ysp, const u16* __restrict__ wunp,
                         const float* __restrict__ bun, float* __restrict__ out) {
  int bid = blockIdx.x;  // 1024 = 512 mtiles x 2 d-halves
  int mtile = bid >> 1, dh = bid & 1;
  int b = mtile >> 1, kk0 = (mtile & 1) << 6;
  int w = threadIdx.x >> 6, lane = threadIdx.x & 63, l15 = lane & 15, l4 = lane >> 4;
  int rg = mtile * 4 + w;
  const u16* A = ysp + (size_t)rg * 16384 + (size_t)(lane * 8);
  f32x4 acc[8] = {};
  float bv[8];
#pragma unroll
  for (int nt = 0; nt < 8; ++nt) bv[nt] = bun[dh * 128 + nt * 16 + l15];
#pragma unroll 4
  for (int kc = 0; kc < 32; ++kc) {
    bf16x8 a = *(const bf16x8*)(A + (size_t)kc * 512);
#pragma unroll
    for (int nt = 0; nt < 8; ++nt) {
      const u16* B = wunp + ((size_t)((dh * 8 + nt) * 32 + kc)) * 512 + (size_t)(lane * 8);
      acc[nt] = mfma16(a, *(const bf16x8*)B, acc[nt]);
    }
  }
#pragma unroll
  for (int nt = 0; nt < 8; ++nt) {
    float4 v = {acc[nt][0] + bv[nt], acc[nt][1] + bv[nt], acc[nt][2] + bv[nt],
                acc[nt][3] + bv[nt]};
    int d = dh * 128 + nt * 16 + l15;
    *(float4*)(out + (size_t)b * 32768 + (size_t)d * 128 + kk0 + w * 16 + l4 * 4) = v;
  }
}

// ---------- launch ----------
extern "C" void kernel_launch(void* const* d_in, const int* in_sizes, int n_in,
                              void* d_out, int out_size, void* d_ws, size_t ws_size,
                              hipStream_t stream) {
  const float* c_in = (const float*)d_in[0];
  const float* x_in = (const float*)d_in[2];
  const float* Wih  = (const float*)d_in[3];
  const float* Whh  = (const float*)d_in[4];
  const float* bih  = (const float*)d_in[5];
  const float* bhh  = (const float*)d_in[6];
  const float* Wtok = (const float*)d_in[7];
  const float* btok = (const float*)d_in[8];
  const float* Wun  = (const float*)d_in[9];
  const float* bun  = (const float*)d_in[10];
  float* out = (float*)d_out;
  char* ws = (char*)d_ws;

  const size_t OW_HH = 0;                     // u16 packed [6144 frags][512]
  const size_t OW_C  = 6291456;               // u16 packed [1536 frags][512]
  const size_t OW_UN = 7864320;               // u16 packed [512 frags][512]
  const size_t OBC   = 8388608;               // f32 [3072]
  const size_t OXHI  = 8400896;               // u16 [128][65536]
  const size_t OXLO  = 25178112;
  const size_t OHHI  = 41955328;              // u16 [2][262144]
  const size_t OHLO  = 43003904;
  const size_t OYS   = 44052480;              // u16 packed [65536 frags][512]
  const size_t OBAR  = 111161344;             // u32 [256] barrier state
  const size_t NEED  = 111162368;
  if (ws_size < NEED) return;

  u16* whh_p = (u16*)(ws + OW_HH);
  u16* wc_p  = (u16*)(ws + OW_C);
  u16* wun_p = (u16*)(ws + OW_UN);
  float* bc  = (float*)(ws + OBC);
  u16* xhi   = (u16*)(ws + OXHI);
  u16* xlo   = (u16*)(ws + OXLO);
  u16* hhi   = (u16*)(ws + OHHI);
  u16* hlo   = (u16*)(ws + OHLO);
  u16* ys    = (u16*)(ws + OYS);
  unsigned* bar = (unsigned*)(ws + OBAR);

  k_round<<<1024, 256, 0, stream>>>(Whh, Wun, whh_p, wun_p);
  k_wcomb<<<dim3(48, 4), 256, 0, stream>>>(Wih, Wtok, wc_p);
  k_bcomb<<<3072, 256, 0, stream>>>(Wih, btok, bih, bc);
  k_xprep<<<1024, 256, 0, stream>>>(x_in, xhi, xlo);
  k_hinit<<<1024, 256, 0, stream>>>(c_in, hhi, hlo);
  k_zero<<<1, 256, 0, stream>>>(bar);

  {
    u16* hhi_l = hhi;
    u16* hlo_l = hlo;
    const u16* xhi_l = xhi;
    const u16* xlo_l = xlo;
    const u16* whp_l = whh_p;
    const u16* wcp_l = wc_p;
    const float* bih_l = bih;
    const float* bc_l = bc;
    const float* bhh_l = bhh;
    u16* ys_l = ys;
    unsigned* bar_l = bar;
    void* args[] = {&hhi_l, &hlo_l, &xhi_l, &xlo_l, &whp_l, &wcp_l,
                    &bih_l, &bc_l, &bhh_l, &ys_l, &bar_l};
    hipLaunchCooperativeKernel((const void*)k_gru2, dim3(256), dim3(512), args, 0, stream);
  }

  k_untok3<<<1024, 256, 0, stream>>>(ys, wun_p, bun, out);
}

// Round 13
// 1014.340 us; speedup vs baseline: 1.7820x; 1.1997x over previous
//
#include <hip/hip_runtime.h>
#include <cstdint>

typedef __attribute__((ext_vector_type(8))) short bf16x8;
typedef __attribute__((ext_vector_type(4))) float f32x4;
typedef unsigned short u16;
typedef unsigned long long u64;

// ---------- bf16 helpers (round-to-nearest-even) ----------
__device__ __forceinline__ u16 f2bf(float x) {
  unsigned u = __builtin_bit_cast(unsigned, x);
  return (u16)((u + 0x7FFFu + ((u >> 16) & 1u)) >> 16);
}
__device__ __forceinline__ float bf2f(u16 h) {
  unsigned u = ((unsigned)h) << 16;
  return __builtin_bit_cast(float, u);
}
__device__ __forceinline__ f32x4 mfma16(bf16x8 a, bf16x8 b, f32x4 c) {
  return __builtin_amdgcn_mfma_f32_16x16x32_bf16(a, b, c, 0, 0, 0);
}

// Coherent h exchange (validated r6): relaxed agent-scope atomics.
__device__ __forceinline__ bf16x8 ld_coh8(const u16* p) {
  u64 a = __hip_atomic_load((const u64*)p, __ATOMIC_RELAXED, __HIP_MEMORY_SCOPE_AGENT);
  u64 b = __hip_atomic_load((const u64*)(p + 4), __ATOMIC_RELAXED, __HIP_MEMORY_SCOPE_AGENT);
  ulonglong2 t;
  t.x = a;
  t.y = b;
  return __builtin_bit_cast(bf16x8, t);
}
__device__ __forceinline__ void st_coh16(u16* p, uint4 v) {
  ulonglong2 t = __builtin_bit_cast(ulonglong2, v);
  __hip_atomic_store((u64*)p, t.x, __ATOMIC_RELAXED, __HIP_MEMORY_SCOPE_AGENT);
  __hip_atomic_store((u64*)(p + 4), t.y, __ATOMIC_RELAXED, __HIP_MEMORY_SCOPE_AGENT);
}

// Packed MFMA-fragment index for Mat[r][k]: frag=(r>>4)*KC+(k>>5), lane=((k&31)>>3)<<4|(r&15), j=k&7
__device__ __forceinline__ size_t pidx(int r, int k, int KC) {
  return ((size_t)((r >> 4) * KC + (k >> 5))) * 512 +
         (size_t)(((((k & 31) >> 3) << 4) | (r & 15)) * 8) + (size_t)(k & 7);
}
// plane-triple interleaved gate row: orig (p, e) -> ((e>>4)*3+p)*16 + (e&15)
__device__ __forceinline__ int rowperm(int p, int e) {
  return (((e >> 4) * 3 + p) << 4) + (e & 15);
}

// ---------- setup kernels ----------
__global__ void k_round(const float* __restrict__ whh, const float* __restrict__ wun,
                        u16* __restrict__ whhp, u16* __restrict__ wunp) {
  int i = blockIdx.x * 256 + threadIdx.x, st = 1024 * 256;
  for (int j = i; j < 3072 * 1024; j += st) {
    int r = j >> 10, k = j & 1023;
    int p = r >> 10, e = r & 1023;
    whhp[pidx(rowperm(p, e), k, 32)] = f2bf(whh[j]);
  }
  for (int j = i; j < 256 * 1024; j += st) {
    int r = j >> 10, k = j & 1023;
    wunp[pidx(r, k, 32)] = f2bf(wun[j]);
  }
}

__global__ void k_hinit(const float* __restrict__ c, u16* __restrict__ hhi,
                        u16* __restrict__ hlo) {
  int i = blockIdx.x * 256 + threadIdx.x;  // 262144
  int b = i >> 10, e = i & 1023;
  float v = c[i];
  u16 hi = f2bf(v);
  size_t o = pidx(b, e, 32);
  hhi[o] = hi;
  hlo[o] = f2bf(v - bf2f(hi));
}

__global__ void k_zero(unsigned* __restrict__ bar) { bar[threadIdx.x] = 0u; }

// W_comb = W_ih @ W_tok -> packed bf16 frags (KC=8), plane-interleaved rows
__global__ void k_wcomb(const float* __restrict__ wih, const float* __restrict__ wtok,
                        u16* __restrict__ wcb) {
  __shared__ float la[64][33];
  __shared__ float lb[32][65];
  int i0 = blockIdx.x << 6, j0 = blockIdx.y << 6;
  int tid = threadIdx.x;
  int ty = tid >> 4, tx = tid & 15;
  float acc[4][4] = {};
  for (int k0 = 0; k0 < 1024; k0 += 32) {
    __syncthreads();
#pragma unroll
    for (int i = 0; i < 8; ++i) {
      int r = (tid >> 5) + i * 8, cc = tid & 31;
      la[r][cc] = wih[(size_t)(i0 + r) * 1024 + k0 + cc];
    }
#pragma unroll
    for (int i = 0; i < 8; ++i) {
      int idx = i * 256 + tid;
      int r = idx >> 6, cc = idx & 63;
      lb[r][cc] = wtok[(size_t)(k0 + r) * 256 + j0 + cc];
    }
    __syncthreads();
#pragma unroll
    for (int kk = 0; kk < 32; ++kk) {
      float av[4], bv[4];
#pragma unroll
      for (int ii = 0; ii < 4; ++ii) av[ii] = la[ty * 4 + ii][kk];
#pragma unroll
      for (int jj = 0; jj < 4; ++jj) bv[jj] = lb[kk][tx * 4 + jj];
#pragma unroll
      for (int ii = 0; ii < 4; ++ii)
#pragma unroll
        for (int jj = 0; jj < 4; ++jj) acc[ii][jj] += av[ii] * bv[jj];
    }
  }
#pragma unroll
  for (int ii = 0; ii < 4; ++ii)
#pragma unroll
    for (int jj = 0; jj < 4; ++jj) {
      int r = i0 + ty * 4 + ii;
      int p = r >> 10, e = r & 1023;
      wcb[pidx(rowperm(p, e), j0 + tx * 4 + jj, 8)] = f2bf(acc[ii][jj]);
    }
}

__global__ void k_bcomb(const float* __restrict__ wih, const float* __restrict__ btok,
                        const float* __restrict__ bih, float* __restrict__ bc) {
  __shared__ float red[256];
  int j = blockIdx.x, t = threadIdx.x;
  float s = 0.f;
  for (int e = t; e < 1024; e += 256) s += wih[(size_t)j * 1024 + e] * btok[e];
  red[t] = s;
  __syncthreads();
  for (int off = 128; off > 0; off >>= 1) {
    if (t < off) red[t] += red[t + off];
    __syncthreads();
  }
  if (t == 0) bc[j] = red[0] + bih[j];
}

// x packed per step-slice (KC=8): slice k holds x[:, :, 127+k] for k in [1,128)
__global__ void k_xprep(const float* __restrict__ x, u16* __restrict__ xhi,
                        u16* __restrict__ xlo) {
  __shared__ float t[64][129];
  int bid = blockIdx.x;
  int b = bid >> 2, d0 = (bid & 3) << 6;
  int tid = threadIdx.x;
#pragma unroll
  for (int i = 0; i < 32; ++i) {
    int idx = i * 256 + tid;
    int dd = idx >> 7, tt = idx & 127;
    t[dd][tt] = x[(size_t)b * 65536 + (size_t)(d0 + dd) * 256 + 128 + tt];
  }
  __syncthreads();
#pragma unroll
  for (int i = 0; i < 32; ++i) {
    int idx = i * 256 + tid;
    int dd = idx & 63, kk = idx >> 6;
    if (kk < 127) {
      float v = t[dd][kk];
      u16 hi = f2bf(v);
      size_t o = (size_t)(kk + 1) * 65536 + pidx(b, d0 + dd, 8);
      xhi[o] = hi;
      xlo[o] = f2bf(v - bf2f(hi));
    }
  }
}

// ---------- persistent recurrence: 8 XCD-local groups of 32 rows, Ew=32 ----------
// 256 WGs x 512 thr. g=bid&7 (group/XCD), q=bid>>3 (e-superslice, 32 cols).
// WG: rows [g*32,+32), e-cols [q*32,+32), 3 planes + x-plane.
// W: cols [q*32, q*32+16) LDS-resident; cols [+16,+32) streamed (plain cached,
// per-XCD L2-resident 3.75MB). h: hi-only matmul via relaxed agent atomics
// (16MB/step chip-wide, halved vs r12). Waves = (mw 2) x (ks 4 K-split); fold
// via 3-round sequential LDS reduction (deterministic).
__launch_bounds__(512, 1)
__global__ void k_gru5(u16* __restrict__ hhi, u16* __restrict__ hlo,
                       const u16* __restrict__ xhi, const u16* __restrict__ xlo,
                       const u16* __restrict__ whp, const u16* __restrict__ wcp,
                       const float* __restrict__ bih, const float* __restrict__ bcb,
                       const float* __restrict__ bhh, u16* __restrict__ ys,
                       unsigned* __restrict__ bar) {
  __shared__ __align__(16) u16 lwh[3][32][512];  // 96KB  (eb16 = 2q)
  __shared__ __align__(16) u16 lwc[3][8][512];   // 24KB  (eb16 = 2q)
  __shared__ __align__(16) float red[2][8][256]; // 16KB  [mw][eb*4+gate][frag]
  __shared__ __align__(16) u16 sth[32][40];      // 2.5KB (pad 40 keeps 16B chunks aligned)
  __shared__ __align__(16) u16 stl[32][40];      // 2.5KB
  __shared__ u16 hold_h[32][36];                 // 2.25KB
  __shared__ u16 hold_l[32][36];                 // 2.25KB

  int bid = blockIdx.x;
  int g = bid & 7, q = bid >> 3;
  int tid = threadIdx.x;
  int w = tid >> 6, lane = tid & 63, l15 = lane & 15, l4 = lane >> 4;
  int mw = w & 1, ks = w >> 1;  // mw: 16-row half, ks: 4-way K-split

  // LDS W: frags for rows 6q..6q+2 are contiguous (96 whh frags + 24 wc frags)
  {
    const u16* s1 = whp + (size_t)(6 * q) * 32 * 512;
    u16* d1 = &lwh[0][0][0];
#pragma unroll
    for (int i = 0; i < 12; ++i)
      *(uint4*)(d1 + i * 4096 + tid * 8) = *(const uint4*)(s1 + i * 4096 + tid * 8);
    const u16* s2 = wcp + (size_t)(6 * q) * 8 * 512;
    u16* d2 = &lwc[0][0][0];
#pragma unroll
    for (int i = 0; i < 3; ++i)
      *(uint4*)(d2 + i * 4096 + tid * 8) = *(const uint4*)(s2 + i * 4096 + tid * 8);
  }
  __syncthreads();

  // biases for both e-blocks this thread finalizes (only ks==0 uses them)
  float bAr[2], bAz[2], bAn[2], bBr[2], bBz[2], bBn[2], bhn_[2];
#pragma unroll
  for (int eb = 0; eb < 2; ++eb) {
    int e = q * 32 + eb * 16 + l15;
    float hr = bhh[e], hz = bhh[1024 + e];
    bhn_[eb] = bhh[2048 + e];
    bAr[eb] = bih[e] + hr;
    bAz[eb] = bih[1024 + e] + hz;
    bAn[eb] = bih[2048 + e];
    bBr[eb] = bcb[e] + hr;
    bBz[eb] = bcb[1024 + e] + hz;
    bBn[eb] = bcb[2048 + e];
  }

  unsigned* cnt_p = bar + g * 32;
  unsigned* gen_p = bar + g * 32 + 16;

  int rg = g * 2 + mw;  // 16-row frag group for this wave's A operand
  // streamed W pointers (rows 6q+3..6q+5 = eb16 2q+1), plain cached / L2-resident
  const u16* Bs0 = whp + (size_t)(6 * q + 3) * 32 * 512 + (size_t)(lane * 8);
  const u16* Bs1 = whp + (size_t)(6 * q + 4) * 32 * 512 + (size_t)(lane * 8);
  const u16* Bs2 = whp + (size_t)(6 * q + 5) * 32 * 512 + (size_t)(lane * 8);
  const u16* Cs0 = wcp + (size_t)(6 * q + 3) * 8 * 512 + (size_t)(lane * 8);
  const u16* Cs1 = wcp + (size_t)(6 * q + 4) * 8 * 512 + (size_t)(lane * 8);
  const u16* Cs2 = wcp + (size_t)(6 * q + 5) * 8 * 512 + (size_t)(lane * 8);

  for (int k = 0; k < 128; ++k) {
    int cur = k & 1, nxt = cur ^ 1;

    f32x4 R0{}, Z0{}, N0{}, X0{}, R1{}, Z1{}, N1{}, X1{};

    // ---- x-part FIRST (no h dependency): overlaps barrier wait ----
    if (k > 0) {
      const u16* Xh = xhi + (size_t)k * 65536 + (size_t)rg * 4096 + (size_t)(lane * 8);
      const u16* Xl = xlo + (size_t)k * 65536 + (size_t)rg * 4096 + (size_t)(lane * 8);
#pragma unroll
      for (int c = 0; c < 2; ++c) {
        int kc = ks * 2 + c;
        bf16x8 ah = *(const bf16x8*)(Xh + (size_t)kc * 512);
        bf16x8 al = *(const bf16x8*)(Xl + (size_t)kc * 512);
        bf16x8 c00 = *(const bf16x8*)&lwc[0][kc][lane * 8];
        bf16x8 c10 = *(const bf16x8*)&lwc[1][kc][lane * 8];
        bf16x8 c20 = *(const bf16x8*)&lwc[2][kc][lane * 8];
        bf16x8 c01 = *(const bf16x8*)(Cs0 + (size_t)kc * 512);
        bf16x8 c11 = *(const bf16x8*)(Cs1 + (size_t)kc * 512);
        bf16x8 c21 = *(const bf16x8*)(Cs2 + (size_t)kc * 512);
        R0 = mfma16(ah, c00, R0); R0 = mfma16(al, c00, R0);
        Z0 = mfma16(ah, c10, Z0); Z0 = mfma16(al, c10, Z0);
        X0 = mfma16(ah, c20, X0); X0 = mfma16(al, c20, X0);
        R1 = mfma16(ah, c01, R1); R1 = mfma16(al, c01, R1);
        Z1 = mfma16(ah, c11, Z1); Z1 = mfma16(al, c11, Z1);
        X1 = mfma16(ah, c21, X1); X1 = mfma16(al, c21, X1);
      }
      // ---- group barrier wait (32 WGs, XCD-local): relaxed spin only ----
      if (tid == 0) {
        while (__hip_atomic_load(gen_p, __ATOMIC_RELAXED, __HIP_MEMORY_SCOPE_AGENT) <
               (unsigned)k) {
          __builtin_amdgcn_s_sleep(2);
        }
      }
      __syncthreads();
    }

    // ---- h-part: HI only; A coherent-atomic (distinct per wave), B LDS + streamed ----
    const u16* Hh = hhi + (size_t)cur * 262144 + (size_t)rg * 16384 + (size_t)(lane * 8);
#pragma unroll
    for (int c = 0; c < 8; ++c) {
      int kk = ks * 8 + c;
      bf16x8 ah = ld_coh8(Hh + (size_t)kk * 512);
      bf16x8 b00 = *(const bf16x8*)&lwh[0][kk][lane * 8];
      bf16x8 b10 = *(const bf16x8*)&lwh[1][kk][lane * 8];
      bf16x8 b20 = *(const bf16x8*)&lwh[2][kk][lane * 8];
      bf16x8 b01 = *(const bf16x8*)(Bs0 + (size_t)kk * 512);
      bf16x8 b11 = *(const bf16x8*)(Bs1 + (size_t)kk * 512);
      bf16x8 b21 = *(const bf16x8*)(Bs2 + (size_t)kk * 512);
      R0 = mfma16(ah, b00, R0);
      Z0 = mfma16(ah, b10, Z0);
      N0 = mfma16(ah, b20, N0);
      R1 = mfma16(ah, b01, R1);
      Z1 = mfma16(ah, b11, Z1);
      N1 = mfma16(ah, b21, N1);
    }

    // ---- fold round 1: ks==3 writes red (+ hold stash) ----
    if (ks == 3) {
      size_t ho = (size_t)cur * 262144 + (size_t)(rg * 32 + q) * 512 + (size_t)(lane * 8);
      bf16x8 hh = ld_coh8(hhi + ho);
      bf16x8 hl = ld_coh8(hlo + ho);
      int r15 = lane & 15, oct = lane >> 4;
#pragma unroll
      for (int j = 0; j < 8; ++j) {
        hold_h[mw * 16 + r15][oct * 8 + j] = (u16)hh[j];
        hold_l[mw * 16 + r15][oct * 8 + j] = (u16)hl[j];
      }
      *(f32x4*)&red[mw][0][lane * 4] = R0;
      *(f32x4*)&red[mw][1][lane * 4] = Z0;
      *(f32x4*)&red[mw][2][lane * 4] = N0;
      *(f32x4*)&red[mw][3][lane * 4] = X0;
      *(f32x4*)&red[mw][4][lane * 4] = R1;
      *(f32x4*)&red[mw][5][lane * 4] = Z1;
      *(f32x4*)&red[mw][6][lane * 4] = N1;
      *(f32x4*)&red[mw][7][lane * 4] = X1;
    }
    __syncthreads();
    if (ks == 2) {
      *(f32x4*)&red[mw][0][lane * 4] = R0 + *(const f32x4*)&red[mw][0][lane * 4];
      *(f32x4*)&red[mw][1][lane * 4] = Z0 + *(const f32x4*)&red[mw][1][lane * 4];
      *(f32x4*)&red[mw][2][lane * 4] = N0 + *(const f32x4*)&red[mw][2][lane * 4];
      *(f32x4*)&red[mw][3][lane * 4] = X0 + *(const f32x4*)&red[mw][3][lane * 4];
      *(f32x4*)&red[mw][4][lane * 4] = R1 + *(const f32x4*)&red[mw][4][lane * 4];
      *(f32x4*)&red[mw][5][lane * 4] = Z1 + *(const f32x4*)&red[mw][5][lane * 4];
      *(f32x4*)&red[mw][6][lane * 4] = N1 + *(const f32x4*)&red[mw][6][lane * 4];
      *(f32x4*)&red[mw][7][lane * 4] = X1 + *(const f32x4*)&red[mw][7][lane * 4];
    }
    __syncthreads();
    if (ks == 1) {
      *(f32x4*)&red[mw][0][lane * 4] = R0 + *(const f32x4*)&red[mw][0][lane * 4];
      *(f32x4*)&red[mw][1][lane * 4] = Z0 + *(const f32x4*)&red[mw][1][lane * 4];
      *(f32x4*)&red[mw][2][lane * 4] = N0 + *(const f32x4*)&red[mw][2][lane * 4];
      *(f32x4*)&red[mw][3][lane * 4] = X0 + *(const f32x4*)&red[mw][3][lane * 4];
      *(f32x4*)&red[mw][4][lane * 4] = R1 + *(const f32x4*)&red[mw][4][lane * 4];
      *(f32x4*)&red[mw][5][lane * 4] = Z1 + *(const f32x4*)&red[mw][5][lane * 4];
      *(f32x4*)&red[mw][6][lane * 4] = N1 + *(const f32x4*)&red[mw][6][lane * 4];
      *(f32x4*)&red[mw][7][lane * 4] = X1 + *(const f32x4*)&red[mw][7][lane * 4];
    }
    __syncthreads();
    if (ks == 0) {
      f32x4 vR0 = R0 + *(const f32x4*)&red[mw][0][lane * 4];
      f32x4 vZ0 = Z0 + *(const f32x4*)&red[mw][1][lane * 4];
      f32x4 vN0 = N0 + *(const f32x4*)&red[mw][2][lane * 4];
      f32x4 vX0 = X0 + *(const f32x4*)&red[mw][3][lane * 4];
      f32x4 vR1 = R1 + *(const f32x4*)&red[mw][4][lane * 4];
      f32x4 vZ1 = Z1 + *(const f32x4*)&red[mw][5][lane * 4];
      f32x4 vN1 = N1 + *(const f32x4*)&red[mw][6][lane * 4];
      f32x4 vX1 = X1 + *(const f32x4*)&red[mw][7][lane * 4];
#pragma unroll
      for (int eb = 0; eb < 2; ++eb) {
        f32x4 vR = eb ? vR1 : vR0;
        f32x4 vZ = eb ? vZ1 : vZ0;
        f32x4 vN = eb ? vN1 : vN0;
        f32x4 vX = eb ? vX1 : vX0;
        float bir = k ? bBr[eb] : bAr[eb];
        float biz = k ? bBz[eb] : bAz[eb];
        float bin = k ? bBn[eb] : bAn[eb];
        int e64 = eb * 16 + l15;
#pragma unroll
        for (int j = 0; j < 4; ++j) {
          int row_rel = mw * 16 + l4 * 4 + j;
          float hold = bf2f(hold_h[row_rel][e64]) + bf2f(hold_l[row_rel][e64]);
          float gr = vR[j] + bir;
          float gz = vZ[j] + biz;
          float gh = vN[j] + bhn_[eb];
          float gx = vX[j] + bin;
          float r = 1.f / (1.f + __expf(-gr));
          float z = 1.f / (1.f + __expf(-gz));
          float n = 1.f - 2.f / (1.f + __expf(2.f * (gx + r * gh)));
          float h = (1.f - z) * n + z * hold;
          u16 hi = f2bf(h);
          sth[row_rel][e64] = hi;
          stl[row_rel][e64] = f2bf(h - bf2f(hi));
        }
      }
    }
    __syncthreads();

    // ---- stores: h = 2 full frags (rg*32+q) hi+lo (write-through), ys (plain) ----
    if (tid < 256) {
      int mws = (tid >> 6) & 1, isLo = tid >> 7, l = tid & 63;
      int r15 = l & 15, oct = l >> 4;
      size_t off = (size_t)((g * 2 + mws) * 32 + q) * 512 + (size_t)(l * 8);
      const u16* src = isLo ? &stl[mws * 16 + r15][oct * 8] : &sth[mws * 16 + r15][oct * 8];
      u16* dst = (isLo ? hlo : hhi) + (size_t)nxt * 262144;
      st_coh16(dst + off, *(const uint4*)src);
    } else if (tid < 384) {
      int cc = tid - 256;             // [0,128): 32 rows x 4 chunks
      int b_rel = cc >> 2, oct = cc & 3;
      size_t f = (size_t)((g * 32 + b_rel) * 8 + (k >> 4)) * 32 + (size_t)q;
      *(uint4*)(ys + f * 512 + (size_t)(((oct << 4) | (k & 15)) * 8)) =
          *(const uint4*)&sth[b_rel][oct * 8];
    }

    if (k < 127) {
      // drain stores (syncthreads waits vmcnt(0) before s_barrier), then relaxed arrive
      __syncthreads();
      if (tid == 0) {
        unsigned t = __hip_atomic_fetch_add(cnt_p, 1u, __ATOMIC_RELAXED,
                                            __HIP_MEMORY_SCOPE_AGENT);
        if (t == (unsigned)(k + 1) * 32u - 1u)
          __hip_atomic_store(gen_p, (unsigned)(k + 1), __ATOMIC_RELAXED,
                             __HIP_MEMORY_SCOPE_AGENT);
      }
    }
  }
}

// ---------- untokenizer: packed frags, direct full-line float4 stores, no big LDS ----------
__launch_bounds__(256, 4)
__global__ void k_untok3(const u16* __restrict__ ysp, const u16* __restrict__ wunp,
                         const float* __restrict__ bun, float* __restrict__ out) {
  int bid = blockIdx.x;  // 1024 = 512 mtiles x 2 d-halves
  int mtile = bid >> 1, dh = bid & 1;
  int b = mtile >> 1, kk0 = (mtile & 1) << 6;
  int w = threadIdx.x >> 6, lane = threadIdx.x & 63, l15 = lane & 15, l4 = lane >> 4;
  int rg = mtile * 4 + w;
  const u16* A = ysp + (size_t)rg * 16384 + (size_t)(lane * 8);
  f32x4 acc[8] = {};
  float bv[8];
#pragma unroll
  for (int nt = 0; nt < 8; ++nt) bv[nt] = bun[dh * 128 + nt * 16 + l15];
#pragma unroll 4
  for (int kc = 0; kc < 32; ++kc) {
    bf16x8 a = *(const bf16x8*)(A + (size_t)kc * 512);
#pragma unroll
    for (int nt = 0; nt < 8; ++nt) {
      const u16* B = wunp + ((size_t)((dh * 8 + nt) * 32 + kc)) * 512 + (size_t)(lane * 8);
      acc[nt] = mfma16(a, *(const bf16x8*)B, acc[nt]);
    }
  }
#pragma unroll
  for (int nt = 0; nt < 8; ++nt) {
    float4 v = {acc[nt][0] + bv[nt], acc[nt][1] + bv[nt], acc[nt][2] + bv[nt],
                acc[nt][3] + bv[nt]};
    int d = dh * 128 + nt * 16 + l15;
    *(float4*)(out + (size_t)b * 32768 + (size_t)d * 128 + kk0 + w * 16 + l4 * 4) = v;
  }
}

// ---------- launch ----------
extern "C" void kernel_launch(void* const* d_in, const int* in_sizes, int n_in,
                              void* d_out, int out_size, void* d_ws, size_t ws_size,
                              hipStream_t stream) {
  const float* c_in = (const float*)d_in[0];
  const float* x_in = (const float*)d_in[2];
  const float* Wih  = (const float*)d_in[3];
  const float* Whh  = (const float*)d_in[4];
  const float* bih  = (const float*)d_in[5];
  const float* bhh  = (const float*)d_in[6];
  const float* Wtok = (const float*)d_in[7];
  const float* btok = (const float*)d_in[8];
  const float* Wun  = (const float*)d_in[9];
  const float* bun  = (const float*)d_in[10];
  float* out = (float*)d_out;
  char* ws = (char*)d_ws;

  const size_t OW_HH = 0;                     // u16 packed [6144 frags][512]
  const size_t OW_C  = 6291456;               // u16 packed [1536 frags][512]
  const size_t OW_UN = 7864320;               // u16 packed [512 frags][512]
  const size_t OBC   = 8388608;               // f32 [3072]
  const size_t OXHI  = 8400896;               // u16 [128][65536]
  const size_t OXLO  = 25178112;
  const size_t OHHI  = 41955328;              // u16 [2][262144]
  const size_t OHLO  = 43003904;
  const size_t OYS   = 44052480;              // u16 packed [65536 frags][512]
  const size_t OBAR  = 111161344;             // u32 [256] barrier state
  const size_t NEED  = 111162368;
  if (ws_size < NEED) return;

  u16* whh_p = (u16*)(ws + OW_HH);
  u16* wc_p  = (u16*)(ws + OW_C);
  u16* wun_p = (u16*)(ws + OW_UN);
  float* bc  = (float*)(ws + OBC);
  u16* xhi   = (u16*)(ws + OXHI);
  u16* xlo   = (u16*)(ws + OXLO);
  u16* hhi   = (u16*)(ws + OHHI);
  u16* hlo   = (u16*)(ws + OHLO);
  u16* ys    = (u16*)(ws + OYS);
  unsigned* bar = (unsigned*)(ws + OBAR);

  k_round<<<1024, 256, 0, stream>>>(Whh, Wun, whh_p, wun_p);
  k_wcomb<<<dim3(48, 4), 256, 0, stream>>>(Wih, Wtok, wc_p);
  k_bcomb<<<3072, 256, 0, stream>>>(Wih, btok, bih, bc);
  k_xprep<<<1024, 256, 0, stream>>>(x_in, xhi, xlo);
  k_hinit<<<1024, 256, 0, stream>>>(c_in, hhi, hlo);
  k_zero<<<1, 256, 0, stream>>>(bar);

  {
    u16* hhi_l = hhi;
    u16* hlo_l = hlo;
    const u16* xhi_l = xhi;
    const u16* xlo_l = xlo;
    const u16* whp_l = whh_p;
    const u16* wcp_l = wc_p;
    const float* bih_l = bih;
    const float* bc_l = bc;
    const float* bhh_l = bhh;
    u16* ys_l = ys;
    unsigned* bar_l = bar;
    void* args[] = {&hhi_l, &hlo_l, &xhi_l, &xlo_l, &whp_l, &wcp_l,
                    &bih_l, &bc_l, &bhh_l, &ys_l, &bar_l};
    hipLaunchCooperativeKernel((const void*)k_gru5, dim3(256), dim3(512), args, 0, stream);
  }

  k_untok3<<<1024, 256, 0, stream>>>(ys, wun_p, bun, out);
}

// Round 15
// 919.836 us; speedup vs baseline: 1.9651x; 1.1027x over previous
//
#include <hip/hip_runtime.h>
#include <cstdint>

typedef __attribute__((ext_vector_type(8))) short bf16x8;
typedef __attribute__((ext_vector_type(4))) float f32x4;
typedef unsigned short u16;
typedef unsigned long long u64;

// ---------- bf16 helpers (round-to-nearest-even) ----------
__device__ __forceinline__ u16 f2bf(float x) {
  unsigned u = __builtin_bit_cast(unsigned, x);
  return (u16)((u + 0x7FFFu + ((u >> 16) & 1u)) >> 16);
}
__device__ __forceinline__ float bf2f(u16 h) {
  unsigned u = ((unsigned)h) << 16;
  return __builtin_bit_cast(float, u);
}
__device__ __forceinline__ f32x4 mfma16(bf16x8 a, bf16x8 b, f32x4 c) {
  return __builtin_amdgcn_mfma_f32_16x16x32_bf16(a, b, c, 0, 0, 0);
}

// Coherent h exchange (validated r6): relaxed agent-scope atomics.
__device__ __forceinline__ bf16x8 ld_coh8(const u16* p) {
  u64 a = __hip_atomic_load((const u64*)p, __ATOMIC_RELAXED, __HIP_MEMORY_SCOPE_AGENT);
  u64 b = __hip_atomic_load((const u64*)(p + 4), __ATOMIC_RELAXED, __HIP_MEMORY_SCOPE_AGENT);
  ulonglong2 t;
  t.x = a;
  t.y = b;
  return __builtin_bit_cast(bf16x8, t);
}
__device__ __forceinline__ void st_coh16(u16* p, uint4 v) {
  ulonglong2 t = __builtin_bit_cast(ulonglong2, v);
  __hip_atomic_store((u64*)p, t.x, __ATOMIC_RELAXED, __HIP_MEMORY_SCOPE_AGENT);
  __hip_atomic_store((u64*)(p + 4), t.y, __ATOMIC_RELAXED, __HIP_MEMORY_SCOPE_AGENT);
}

// Packed MFMA-fragment index for Mat[r][k]: frag=(r>>4)*KC+(k>>5), lane=((k&31)>>3)<<4|(r&15), j=k&7
__device__ __forceinline__ size_t pidx(int r, int k, int KC) {
  return ((size_t)((r >> 4) * KC + (k >> 5))) * 512 +
         (size_t)(((((k & 31) >> 3) << 4) | (r & 15)) * 8) + (size_t)(k & 7);
}
// plane-triple interleaved gate row: orig (p, e) -> ((e>>4)*3+p)*16 + (e&15)
__device__ __forceinline__ int rowperm(int p, int e) {
  return (((e >> 4) * 3 + p) << 4) + (e & 15);
}

// ---------- setup kernels ----------
__global__ void k_round(const float* __restrict__ whh, const float* __restrict__ wun,
                        u16* __restrict__ whhp, u16* __restrict__ wunp) {
  int i = blockIdx.x * 256 + threadIdx.x, st = 1024 * 256;
  for (int j = i; j < 3072 * 1024; j += st) {
    int r = j >> 10, k = j & 1023;
    int p = r >> 10, e = r & 1023;
    whhp[pidx(rowperm(p, e), k, 32)] = f2bf(whh[j]);
  }
  for (int j = i; j < 256 * 1024; j += st) {
    int r = j >> 10, k = j & 1023;
    wunp[pidx(r, k, 32)] = f2bf(wun[j]);
  }
}

__global__ void k_hinit(const float* __restrict__ c, u16* __restrict__ hhi,
                        u16* __restrict__ hlo) {
  int i = blockIdx.x * 256 + threadIdx.x;  // 262144
  int b = i >> 10, e = i & 1023;
  float v = c[i];
  u16 hi = f2bf(v);
  size_t o = pidx(b, e, 32);
  hhi[o] = hi;
  hlo[o] = f2bf(v - bf2f(hi));
}

__global__ void k_zero(unsigned* __restrict__ bar) { bar[threadIdx.x] = 0u; }

// W_comb = W_ih @ W_tok -> packed bf16 frags (KC=8), plane-interleaved rows
__global__ void k_wcomb(const float* __restrict__ wih, const float* __restrict__ wtok,
                        u16* __restrict__ wcb) {
  __shared__ float la[64][33];
  __shared__ float lb[32][65];
  int i0 = blockIdx.x << 6, j0 = blockIdx.y << 6;
  int tid = threadIdx.x;
  int ty = tid >> 4, tx = tid & 15;
  float acc[4][4] = {};
  for (int k0 = 0; k0 < 1024; k0 += 32) {
    __syncthreads();
#pragma unroll
    for (int i = 0; i < 8; ++i) {
      int r = (tid >> 5) + i * 8, cc = tid & 31;
      la[r][cc] = wih[(size_t)(i0 + r) * 1024 + k0 + cc];
    }
#pragma unroll
    for (int i = 0; i < 8; ++i) {
      int idx = i * 256 + tid;
      int r = idx >> 6, cc = idx & 63;
      lb[r][cc] = wtok[(size_t)(k0 + r) * 256 + j0 + cc];
    }
    __syncthreads();
#pragma unroll
    for (int kk = 0; kk < 32; ++kk) {
      float av[4], bv[4];
#pragma unroll
      for (int ii = 0; ii < 4; ++ii) av[ii] = la[ty * 4 + ii][kk];
#pragma unroll
      for (int jj = 0; jj < 4; ++jj) bv[jj] = lb[kk][tx * 4 + jj];
#pragma unroll
      for (int ii = 0; ii < 4; ++ii)
#pragma unroll
        for (int jj = 0; jj < 4; ++jj) acc[ii][jj] += av[ii] * bv[jj];
    }
  }
#pragma unroll
  for (int ii = 0; ii < 4; ++ii)
#pragma unroll
    for (int jj = 0; jj < 4; ++jj) {
      int r = i0 + ty * 4 + ii;
      int p = r >> 10, e = r & 1023;
      wcb[pidx(rowperm(p, e), j0 + tx * 4 + jj, 8)] = f2bf(acc[ii][jj]);
    }
}

__global__ void k_bcomb(const float* __restrict__ wih, const float* __restrict__ btok,
                        const float* __restrict__ bih, float* __restrict__ bc) {
  __shared__ float red[256];
  int j = blockIdx.x, t = threadIdx.x;
  float s = 0.f;
  for (int e = t; e < 1024; e += 256) s += wih[(size_t)j * 1024 + e] * btok[e];
  red[t] = s;
  __syncthreads();
  for (int off = 128; off > 0; off >>= 1) {
    if (t < off) red[t] += red[t + off];
    __syncthreads();
  }
  if (t == 0) bc[j] = red[0] + bih[j];
}

// x packed per step-slice (KC=8): slice k holds x[:, :, 127+k] for k in [1,128)
__global__ void k_xprep(const float* __restrict__ x, u16* __restrict__ xhi,
                        u16* __restrict__ xlo) {
  __shared__ float t[64][129];
  int bid = blockIdx.x;
  int b = bid >> 2, d0 = (bid & 3) << 6;
  int tid = threadIdx.x;
#pragma unroll
  for (int i = 0; i < 32; ++i) {
    int idx = i * 256 + tid;
    int dd = idx >> 7, tt = idx & 127;
    t[dd][tt] = x[(size_t)b * 65536 + (size_t)(d0 + dd) * 256 + 128 + tt];
  }
  __syncthreads();
#pragma unroll
  for (int i = 0; i < 32; ++i) {
    int idx = i * 256 + tid;
    int dd = idx & 63, kk = idx >> 6;
    if (kk < 127) {
      float v = t[dd][kk];
      u16 hi = f2bf(v);
      size_t o = (size_t)(kk + 1) * 65536 + pidx(b, d0 + dd, 8);
      xhi[o] = hi;
      xlo[o] = f2bf(v - bf2f(hi));
    }
  }
}

// ---------- persistent recurrence: r13 structure + {streamed-W reg prefetch, batched h loads} ----------
// 256 WGs x 512 thr. g=bid&7 (group/XCD), q=bid>>3 (e-superslice, 32 cols).
// WG: rows [g*32,+32), e-cols [q*32,+32), 3 planes + x-plane.
// W: cols [q*32,+16) LDS-resident; cols [+16,+32) streamed from per-XCD L2 —
// NOW prefetched to registers BEFORE the barrier spin (overlaps wait).
// h: hi-only matmul via relaxed agent atomics — NOW batched (8 outstanding).
// Waves = (mw 2) x (ks 4 K-split); 3-round sequential LDS fold (unchanged from r13).
__launch_bounds__(512, 1)
__global__ void k_gru5(u16* __restrict__ hhi, u16* __restrict__ hlo,
                       const u16* __restrict__ xhi, const u16* __restrict__ xlo,
                       const u16* __restrict__ whp, const u16* __restrict__ wcp,
                       const float* __restrict__ bih, const float* __restrict__ bcb,
                       const float* __restrict__ bhh, u16* __restrict__ ys,
                       unsigned* __restrict__ bar) {
  __shared__ __align__(16) u16 lwh[3][32][512];  // 96KB  (eb16 = 2q)
  __shared__ __align__(16) u16 lwc[3][8][512];   // 24KB  (eb16 = 2q)
  __shared__ __align__(16) float red[2][8][256]; // 16KB  [mw][eb*4+gate][frag]
  __shared__ __align__(16) u16 sth[32][40];      // 2.5KB
  __shared__ __align__(16) u16 stl[32][40];      // 2.5KB
  __shared__ u16 hold_h[32][36];                 // 2.25KB
  __shared__ u16 hold_l[32][36];                 // 2.25KB

  int bid = blockIdx.x;
  int g = bid & 7, q = bid >> 3;
  int tid = threadIdx.x;
  int w = tid >> 6, lane = tid & 63, l15 = lane & 15, l4 = lane >> 4;
  int mw = w & 1, ks = w >> 1;  // mw: 16-row half, ks: 4-way K-split

  // LDS W: frags for rows 6q..6q+2 are contiguous (96 whh frags + 24 wc frags)
  {
    const u16* s1 = whp + (size_t)(6 * q) * 32 * 512;
    u16* d1 = &lwh[0][0][0];
#pragma unroll
    for (int i = 0; i < 12; ++i)
      *(uint4*)(d1 + i * 4096 + tid * 8) = *(const uint4*)(s1 + i * 4096 + tid * 8);
    const u16* s2 = wcp + (size_t)(6 * q) * 8 * 512;
    u16* d2 = &lwc[0][0][0];
#pragma unroll
    for (int i = 0; i < 3; ++i)
      *(uint4*)(d2 + i * 4096 + tid * 8) = *(const uint4*)(s2 + i * 4096 + tid * 8);
  }
  __syncthreads();

  // biases for both e-blocks this thread finalizes (only ks==0 uses them)
  float bAr[2], bAz[2], bAn[2], bBr[2], bBz[2], bBn[2], bhn_[2];
#pragma unroll
  for (int eb = 0; eb < 2; ++eb) {
    int e = q * 32 + eb * 16 + l15;
    float hr = bhh[e], hz = bhh[1024 + e];
    bhn_[eb] = bhh[2048 + e];
    bAr[eb] = bih[e] + hr;
    bAz[eb] = bih[1024 + e] + hz;
    bAn[eb] = bih[2048 + e];
    bBr[eb] = bcb[e] + hr;
    bBz[eb] = bcb[1024 + e] + hz;
    bBn[eb] = bcb[2048 + e];
  }

  unsigned* cnt_p = bar + g * 32;
  unsigned* gen_p = bar + g * 32 + 16;

  int rg = g * 2 + mw;  // 16-row frag group for this wave's A operand
  // streamed W pointers (rows 6q+3..6q+5 = eb16 2q+1), plain cached / L2-resident
  const u16* Bs0 = whp + (size_t)(6 * q + 3) * 32 * 512 + (size_t)(lane * 8);
  const u16* Bs1 = whp + (size_t)(6 * q + 4) * 32 * 512 + (size_t)(lane * 8);
  const u16* Bs2 = whp + (size_t)(6 * q + 5) * 32 * 512 + (size_t)(lane * 8);
  const u16* Cs0 = wcp + (size_t)(6 * q + 3) * 8 * 512 + (size_t)(lane * 8);
  const u16* Cs1 = wcp + (size_t)(6 * q + 4) * 8 * 512 + (size_t)(lane * 8);
  const u16* Cs2 = wcp + (size_t)(6 * q + 5) * 8 * 512 + (size_t)(lane * 8);

  for (int k = 0; k < 128; ++k) {
    int cur = k & 1, nxt = cur ^ 1;

    f32x4 R0{}, Z0{}, N0{}, X0{}, R1{}, Z1{}, N1{}, X1{};

    // ---- NEW (r15): prefetch this wave's streamed-W h-part frags into registers
    //      (plain loads, read-only data, no h dependency -> overlaps barrier wait)
    bf16x8 pb0[8], pb1[8], pb2[8];
#pragma unroll
    for (int c = 0; c < 8; ++c) {
      int kk = ks * 8 + c;
      pb0[c] = *(const bf16x8*)(Bs0 + (size_t)kk * 512);
      pb1[c] = *(const bf16x8*)(Bs1 + (size_t)kk * 512);
      pb2[c] = *(const bf16x8*)(Bs2 + (size_t)kk * 512);
    }

    // ---- x-part FIRST (no h dependency): overlaps barrier wait ----
    if (k > 0) {
      const u16* Xh = xhi + (size_t)k * 65536 + (size_t)rg * 4096 + (size_t)(lane * 8);
      const u16* Xl = xlo + (size_t)k * 65536 + (size_t)rg * 4096 + (size_t)(lane * 8);
#pragma unroll
      for (int c = 0; c < 2; ++c) {
        int kc = ks * 2 + c;
        bf16x8 ah = *(const bf16x8*)(Xh + (size_t)kc * 512);
        bf16x8 al = *(const bf16x8*)(Xl + (size_t)kc * 512);
        bf16x8 c00 = *(const bf16x8*)&lwc[0][kc][lane * 8];
        bf16x8 c10 = *(const bf16x8*)&lwc[1][kc][lane * 8];
        bf16x8 c20 = *(const bf16x8*)&lwc[2][kc][lane * 8];
        bf16x8 c01 = *(const bf16x8*)(Cs0 + (size_t)kc * 512);
        bf16x8 c11 = *(const bf16x8*)(Cs1 + (size_t)kc * 512);
        bf16x8 c21 = *(const bf16x8*)(Cs2 + (size_t)kc * 512);
        R0 = mfma16(ah, c00, R0); R0 = mfma16(al, c00, R0);
        Z0 = mfma16(ah, c10, Z0); Z0 = mfma16(al, c10, Z0);
        X0 = mfma16(ah, c20, X0); X0 = mfma16(al, c20, X0);
        R1 = mfma16(ah, c01, R1); R1 = mfma16(al, c01, R1);
        Z1 = mfma16(ah, c11, Z1); Z1 = mfma16(al, c11, Z1);
        X1 = mfma16(ah, c21, X1); X1 = mfma16(al, c21, X1);
      }
      // ---- group barrier wait (32 WGs, XCD-local): relaxed spin only ----
      if (tid == 0) {
        while (__hip_atomic_load(gen_p, __ATOMIC_RELAXED, __HIP_MEMORY_SCOPE_AGENT) <
               (unsigned)k) {
          __builtin_amdgcn_s_sleep(2);
        }
      }
      __syncthreads();
    }

    // ---- NEW (r15): batched coherent h loads (8 outstanding, one latency ramp) ----
    const u16* Hh = hhi + (size_t)cur * 262144 + (size_t)rg * 16384 + (size_t)(lane * 8);
    bf16x8 ahv[8];
#pragma unroll
    for (int c = 0; c < 8; ++c)
      ahv[c] = ld_coh8(Hh + (size_t)(ks * 8 + c) * 512);

    // ---- h-part: HI only; A = batched regs, B = LDS + prefetched regs ----
#pragma unroll
    for (int c = 0; c < 8; ++c) {
      int kk = ks * 8 + c;
      bf16x8 b00 = *(const bf16x8*)&lwh[0][kk][lane * 8];
      bf16x8 b10 = *(const bf16x8*)&lwh[1][kk][lane * 8];
      bf16x8 b20 = *(const bf16x8*)&lwh[2][kk][lane * 8];
      R0 = mfma16(ahv[c], b00, R0);
      Z0 = mfma16(ahv[c], b10, Z0);
      N0 = mfma16(ahv[c], b20, N0);
      R1 = mfma16(ahv[c], pb0[c], R1);
      Z1 = mfma16(ahv[c], pb1[c], Z1);
      N1 = mfma16(ahv[c], pb2[c], N1);
    }

    // ---- fold round 1: ks==3 writes red (+ hold stash) ----
    if (ks == 3) {
      size_t ho = (size_t)cur * 262144 + (size_t)(rg * 32 + q) * 512 + (size_t)(lane * 8);
      bf16x8 hh = ld_coh8(hhi + ho);
      bf16x8 hl = ld_coh8(hlo + ho);
      int r15 = lane & 15, oct = lane >> 4;
#pragma unroll
      for (int j = 0; j < 8; ++j) {
        hold_h[mw * 16 + r15][oct * 8 + j] = (u16)hh[j];
        hold_l[mw * 16 + r15][oct * 8 + j] = (u16)hl[j];
      }
      *(f32x4*)&red[mw][0][lane * 4] = R0;
      *(f32x4*)&red[mw][1][lane * 4] = Z0;
      *(f32x4*)&red[mw][2][lane * 4] = N0;
      *(f32x4*)&red[mw][3][lane * 4] = X0;
      *(f32x4*)&red[mw][4][lane * 4] = R1;
      *(f32x4*)&red[mw][5][lane * 4] = Z1;
      *(f32x4*)&red[mw][6][lane * 4] = N1;
      *(f32x4*)&red[mw][7][lane * 4] = X1;
    }
    __syncthreads();
    if (ks == 2) {
      *(f32x4*)&red[mw][0][lane * 4] = R0 + *(const f32x4*)&red[mw][0][lane * 4];
      *(f32x4*)&red[mw][1][lane * 4] = Z0 + *(const f32x4*)&red[mw][1][lane * 4];
      *(f32x4*)&red[mw][2][lane * 4] = N0 + *(const f32x4*)&red[mw][2][lane * 4];
      *(f32x4*)&red[mw][3][lane * 4] = X0 + *(const f32x4*)&red[mw][3][lane * 4];
      *(f32x4*)&red[mw][4][lane * 4] = R1 + *(const f32x4*)&red[mw][4][lane * 4];
      *(f32x4*)&red[mw][5][lane * 4] = Z1 + *(const f32x4*)&red[mw][5][lane * 4];
      *(f32x4*)&red[mw][6][lane * 4] = N1 + *(const f32x4*)&red[mw][6][lane * 4];
      *(f32x4*)&red[mw][7][lane * 4] = X1 + *(const f32x4*)&red[mw][7][lane * 4];
    }
    __syncthreads();
    if (ks == 1) {
      *(f32x4*)&red[mw][0][lane * 4] = R0 + *(const f32x4*)&red[mw][0][lane * 4];
      *(f32x4*)&red[mw][1][lane * 4] = Z0 + *(const f32x4*)&red[mw][1][lane * 4];
      *(f32x4*)&red[mw][2][lane * 4] = N0 + *(const f32x4*)&red[mw][2][lane * 4];
      *(f32x4*)&red[mw][3][lane * 4] = X0 + *(const f32x4*)&red[mw][3][lane * 4];
      *(f32x4*)&red[mw][4][lane * 4] = R1 + *(const f32x4*)&red[mw][4][lane * 4];
      *(f32x4*)&red[mw][5][lane * 4] = Z1 + *(const f32x4*)&red[mw][5][lane * 4];
      *(f32x4*)&red[mw][6][lane * 4] = N1 + *(const f32x4*)&red[mw][6][lane * 4];
      *(f32x4*)&red[mw][7][lane * 4] = X1 + *(const f32x4*)&red[mw][7][lane * 4];
    }
    __syncthreads();
    if (ks == 0) {
      f32x4 vR0 = R0 + *(const f32x4*)&red[mw][0][lane * 4];
      f32x4 vZ0 = Z0 + *(const f32x4*)&red[mw][1][lane * 4];
      f32x4 vN0 = N0 + *(const f32x4*)&red[mw][2][lane * 4];
      f32x4 vX0 = X0 + *(const f32x4*)&red[mw][3][lane * 4];
      f32x4 vR1 = R1 + *(const f32x4*)&red[mw][4][lane * 4];
      f32x4 vZ1 = Z1 + *(const f32x4*)&red[mw][5][lane * 4];
      f32x4 vN1 = N1 + *(const f32x4*)&red[mw][6][lane * 4];
      f32x4 vX1 = X1 + *(const f32x4*)&red[mw][7][lane * 4];
#pragma unroll
      for (int eb = 0; eb < 2; ++eb) {
        f32x4 vR = eb ? vR1 : vR0;
        f32x4 vZ = eb ? vZ1 : vZ0;
        f32x4 vN = eb ? vN1 : vN0;
        f32x4 vX = eb ? vX1 : vX0;
        float bir = k ? bBr[eb] : bAr[eb];
        float biz = k ? bBz[eb] : bAz[eb];
        float bin = k ? bBn[eb] : bAn[eb];
        int e64 = eb * 16 + l15;
#pragma unroll
        for (int j = 0; j < 4; ++j) {
          int row_rel = mw * 16 + l4 * 4 + j;
          float hold = bf2f(hold_h[row_rel][e64]) + bf2f(hold_l[row_rel][e64]);
          float gr = vR[j] + bir;
          float gz = vZ[j] + biz;
          float gh = vN[j] + bhn_[eb];
          float gx = vX[j] + bin;
          float r = 1.f / (1.f + __expf(-gr));
          float z = 1.f / (1.f + __expf(-gz));
          float n = 1.f - 2.f / (1.f + __expf(2.f * (gx + r * gh)));
          float h = (1.f - z) * n + z * hold;
          u16 hi = f2bf(h);
          sth[row_rel][e64] = hi;
          stl[row_rel][e64] = f2bf(h - bf2f(hi));
        }
      }
    }
    __syncthreads();

    // ---- stores: h = 2 full frags (rg*32+q) hi+lo (write-through), ys (plain) ----
    if (tid < 256) {
      int mws = (tid >> 6) & 1, isLo = tid >> 7, l = tid & 63;
      int r15 = l & 15, oct = l >> 4;
      size_t off = (size_t)((g * 2 + mws) * 32 + q) * 512 + (size_t)(l * 8);
      const u16* src = isLo ? &stl[mws * 16 + r15][oct * 8] : &sth[mws * 16 + r15][oct * 8];
      u16* dst = (isLo ? hlo : hhi) + (size_t)nxt * 262144;
      st_coh16(dst + off, *(const uint4*)src);
    } else if (tid < 384) {
      int cc = tid - 256;             // [0,128): 32 rows x 4 chunks
      int b_rel = cc >> 2, oct = cc & 3;
      size_t f = (size_t)((g * 32 + b_rel) * 8 + (k >> 4)) * 32 + (size_t)q;
      *(uint4*)(ys + f * 512 + (size_t)(((oct << 4) | (k & 15)) * 8)) =
          *(const uint4*)&sth[b_rel][oct * 8];
    }

    if (k < 127) {
      // drain stores (syncthreads waits vmcnt(0) before s_barrier), then relaxed arrive
      __syncthreads();
      if (tid == 0) {
        unsigned t = __hip_atomic_fetch_add(cnt_p, 1u, __ATOMIC_RELAXED,
                                            __HIP_MEMORY_SCOPE_AGENT);
        if (t == (unsigned)(k + 1) * 32u - 1u)
          __hip_atomic_store(gen_p, (unsigned)(k + 1), __ATOMIC_RELAXED,
                             __HIP_MEMORY_SCOPE_AGENT);
      }
    }
  }
}

// ---------- untokenizer: packed frags, direct full-line float4 stores, no big LDS ----------
__launch_bounds__(256, 4)
__global__ void k_untok3(const u16* __restrict__ ysp, const u16* __restrict__ wunp,
                         const float* __restrict__ bun, float* __restrict__ out) {
  int bid = blockIdx.x;  // 1024 = 512 mtiles x 2 d-halves
  int mtile = bid >> 1, dh = bid & 1;
  int b = mtile >> 1, kk0 = (mtile & 1) << 6;
  int w = threadIdx.x >> 6, lane = threadIdx.x & 63, l15 = lane & 15, l4 = lane >> 4;
  int rg = mtile * 4 + w;
  const u16* A = ysp + (size_t)rg * 16384 + (size_t)(lane * 8);
  f32x4 acc[8] = {};
  float bv[8];
#pragma unroll
  for (int nt = 0; nt < 8; ++nt) bv[nt] = bun[dh * 128 + nt * 16 + l15];
#pragma unroll 4
  for (int kc = 0; kc < 32; ++kc) {
    bf16x8 a = *(const bf16x8*)(A + (size_t)kc * 512);
#pragma unroll
    for (int nt = 0; nt < 8; ++nt) {
      const u16* B = wunp + ((size_t)((dh * 8 + nt) * 32 + kc)) * 512 + (size_t)(lane * 8);
      acc[nt] = mfma16(a, *(const bf16x8*)B, acc[nt]);
    }
  }
#pragma unroll
  for (int nt = 0; nt < 8; ++nt) {
    float4 v = {acc[nt][0] + bv[nt], acc[nt][1] + bv[nt], acc[nt][2] + bv[nt],
                acc[nt][3] + bv[nt]};
    int d = dh * 128 + nt * 16 + l15;
    *(float4*)(out + (size_t)b * 32768 + (size_t)d * 128 + kk0 + w * 16 + l4 * 4) = v;
  }
}

// ---------- launch ----------
extern "C" void kernel_launch(void* const* d_in, const int* in_sizes, int n_in,
                              void* d_out, int out_size, void* d_ws, size_t ws_size,
                              hipStream_t stream) {
  const float* c_in = (const float*)d_in[0];
  const float* x_in = (const float*)d_in[2];
  const float* Wih  = (const float*)d_in[3];
  const float* Whh  = (const float*)d_in[4];
  const float* bih  = (const float*)d_in[5];
  const float* bhh  = (const float*)d_in[6];
  const float* Wtok = (const float*)d_in[7];
  const float* btok = (const float*)d_in[8];
  const float* Wun  = (const float*)d_in[9];
  const float* bun  = (const float*)d_in[10];
  float* out = (float*)d_out;
  char* ws = (char*)d_ws;

  const size_t OW_HH = 0;                     // u16 packed [6144 frags][512]
  const size_t OW_C  = 6291456;               // u16 packed [1536 frags][512]
  const size_t OW_UN = 7864320;               // u16 packed [512 frags][512]
  const size_t OBC   = 8388608;               // f32 [3072]
  const size_t OXHI  = 8400896;               // u16 [128][65536]
  const size_t OXLO  = 25178112;
  const size_t OHHI  = 41955328;              // u16 [2][262144]
  const size_t OHLO  = 43003904;
  const size_t OYS   = 44052480;              // u16 packed [65536 frags][512]
  const size_t OBAR  = 111161344;             // u32 [256] barrier state
  const size_t NEED  = 111162368;
  if (ws_size < NEED) return;

  u16* whh_p = (u16*)(ws + OW_HH);
  u16* wc_p  = (u16*)(ws + OW_C);
  u16* wun_p = (u16*)(ws + OW_UN);
  float* bc  = (float*)(ws + OBC);
  u16* xhi   = (u16*)(ws + OXHI);
  u16* xlo   = (u16*)(ws + OXLO);
  u16* hhi   = (u16*)(ws + OHHI);
  u16* hlo   = (u16*)(ws + OHLO);
  u16* ys    = (u16*)(ws + OYS);
  unsigned* bar = (unsigned*)(ws + OBAR);

  k_round<<<1024, 256, 0, stream>>>(Whh, Wun, whh_p, wun_p);
  k_wcomb<<<dim3(48, 4), 256, 0, stream>>>(Wih, Wtok, wc_p);
  k_bcomb<<<3072, 256, 0, stream>>>(Wih, btok, bih, bc);
  k_xprep<<<1024, 256, 0, stream>>>(x_in, xhi, xlo);
  k_hinit<<<1024, 256, 0, stream>>>(c_in, hhi, hlo);
  k_zero<<<1, 256, 0, stream>>>(bar);

  {
    u16* hhi_l = hhi;
    u16* hlo_l = hlo;
    const u16* xhi_l = xhi;
    const u16* xlo_l = xlo;
    const u16* whp_l = whh_p;
    const u16* wcp_l = wc_p;
    const float* bih_l = bih;
    const float* bc_l = bc;
    const float* bhh_l = bhh;
    u16* ys_l = ys;
    unsigned* bar_l = bar;
    void* args[] = {&hhi_l, &hlo_l, &xhi_l, &xlo_l, &whp_l, &wcp_l,
                    &bih_l, &bc_l, &bhh_l, &ys_l, &bar_l};
    hipLaunchCooperativeKernel((const void*)k_gru5, dim3(256), dim3(512), args, 0, stream);
  }

  k_untok3<<<1024, 256, 0, stream>>>(ys, wun_p, bun, out);
}

// Round 16
// 905.854 us; speedup vs baseline: 1.9955x; 1.0154x over previous
//
#include <hip/hip_runtime.h>
#include <cstdint>

typedef __attribute__((ext_vector_type(8))) short bf16x8;
typedef __attribute__((ext_vector_type(4))) float f32x4;
typedef unsigned short u16;
typedef unsigned long long u64;

// ---------- bf16 helpers (round-to-nearest-even) ----------
__device__ __forceinline__ u16 f2bf(float x) {
  unsigned u = __builtin_bit_cast(unsigned, x);
  return (u16)((u + 0x7FFFu + ((u >> 16) & 1u)) >> 16);
}
__device__ __forceinline__ float bf2f(u16 h) {
  unsigned u = ((unsigned)h) << 16;
  return __builtin_bit_cast(float, u);
}
__device__ __forceinline__ f32x4 mfma16(bf16x8 a, bf16x8 b, f32x4 c) {
  return __builtin_amdgcn_mfma_f32_16x16x32_bf16(a, b, c, 0, 0, 0);
}

// Coherent h exchange (validated r6): relaxed agent-scope atomics.
__device__ __forceinline__ bf16x8 ld_coh8(const u16* p) {
  u64 a = __hip_atomic_load((const u64*)p, __ATOMIC_RELAXED, __HIP_MEMORY_SCOPE_AGENT);
  u64 b = __hip_atomic_load((const u64*)(p + 4), __ATOMIC_RELAXED, __HIP_MEMORY_SCOPE_AGENT);
  ulonglong2 t;
  t.x = a;
  t.y = b;
  return __builtin_bit_cast(bf16x8, t);
}
__device__ __forceinline__ void st_coh16(u16* p, uint4 v) {
  ulonglong2 t = __builtin_bit_cast(ulonglong2, v);
  __hip_atomic_store((u64*)p, t.x, __ATOMIC_RELAXED, __HIP_MEMORY_SCOPE_AGENT);
  __hip_atomic_store((u64*)(p + 4), t.y, __ATOMIC_RELAXED, __HIP_MEMORY_SCOPE_AGENT);
}

// Packed MFMA-fragment index for Mat[r][k]: frag=(r>>4)*KC+(k>>5), lane=((k&31)>>3)<<4|(r&15), j=k&7
__device__ __forceinline__ size_t pidx(int r, int k, int KC) {
  return ((size_t)((r >> 4) * KC + (k >> 5))) * 512 +
         (size_t)(((((k & 31) >> 3) << 4) | (r & 15)) * 8) + (size_t)(k & 7);
}
// plane-triple interleaved gate row: orig (p, e) -> ((e>>4)*3+p)*16 + (e&15)
__device__ __forceinline__ int rowperm(int p, int e) {
  return (((e >> 4) * 3 + p) << 4) + (e & 15);
}

// ---------- setup kernels ----------
__global__ void k_round(const float* __restrict__ whh, const float* __restrict__ wun,
                        u16* __restrict__ whhp, u16* __restrict__ wunp) {
  int i = blockIdx.x * 256 + threadIdx.x, st = 1024 * 256;
  for (int j = i; j < 3072 * 1024; j += st) {
    int r = j >> 10, k = j & 1023;
    int p = r >> 10, e = r & 1023;
    whhp[pidx(rowperm(p, e), k, 32)] = f2bf(whh[j]);
  }
  for (int j = i; j < 256 * 1024; j += st) {
    int r = j >> 10, k = j & 1023;
    wunp[pidx(r, k, 32)] = f2bf(wun[j]);
  }
}

__global__ void k_hinit(const float* __restrict__ c, u16* __restrict__ hhi,
                        u16* __restrict__ hlo) {
  int i = blockIdx.x * 256 + threadIdx.x;  // 262144
  int b = i >> 10, e = i & 1023;
  float v = c[i];
  u16 hi = f2bf(v);
  size_t o = pidx(b, e, 32);
  hhi[o] = hi;
  hlo[o] = f2bf(v - bf2f(hi));
}

__global__ void k_zero(unsigned* __restrict__ bar) {
  bar[blockIdx.x * 256 + threadIdx.x] = 0u;
}

// W_comb = W_ih @ W_tok -> packed bf16 frags (KC=8), plane-interleaved rows
__global__ void k_wcomb(const float* __restrict__ wih, const float* __restrict__ wtok,
                        u16* __restrict__ wcb) {
  __shared__ float la[64][33];
  __shared__ float lb[32][65];
  int i0 = blockIdx.x << 6, j0 = blockIdx.y << 6;
  int tid = threadIdx.x;
  int ty = tid >> 4, tx = tid & 15;
  float acc[4][4] = {};
  for (int k0 = 0; k0 < 1024; k0 += 32) {
    __syncthreads();
#pragma unroll
    for (int i = 0; i < 8; ++i) {
      int r = (tid >> 5) + i * 8, cc = tid & 31;
      la[r][cc] = wih[(size_t)(i0 + r) * 1024 + k0 + cc];
    }
#pragma unroll
    for (int i = 0; i < 8; ++i) {
      int idx = i * 256 + tid;
      int r = idx >> 6, cc = idx & 63;
      lb[r][cc] = wtok[(size_t)(k0 + r) * 256 + j0 + cc];
    }
    __syncthreads();
#pragma unroll
    for (int kk = 0; kk < 32; ++kk) {
      float av[4], bv[4];
#pragma unroll
      for (int ii = 0; ii < 4; ++ii) av[ii] = la[ty * 4 + ii][kk];
#pragma unroll
      for (int jj = 0; jj < 4; ++jj) bv[jj] = lb[kk][tx * 4 + jj];
#pragma unroll
      for (int ii = 0; ii < 4; ++ii)
#pragma unroll
        for (int jj = 0; jj < 4; ++jj) acc[ii][jj] += av[ii] * bv[jj];
    }
  }
#pragma unroll
  for (int ii = 0; ii < 4; ++ii)
#pragma unroll
    for (int jj = 0; jj < 4; ++jj) {
      int r = i0 + ty * 4 + ii;
      int p = r >> 10, e = r & 1023;
      wcb[pidx(rowperm(p, e), j0 + tx * 4 + jj, 8)] = f2bf(acc[ii][jj]);
    }
}

__global__ void k_bcomb(const float* __restrict__ wih, const float* __restrict__ btok,
                        const float* __restrict__ bih, float* __restrict__ bc) {
  __shared__ float red[256];
  int j = blockIdx.x, t = threadIdx.x;
  float s = 0.f;
  for (int e = t; e < 1024; e += 256) s += wih[(size_t)j * 1024 + e] * btok[e];
  red[t] = s;
  __syncthreads();
  for (int off = 128; off > 0; off >>= 1) {
    if (t < off) red[t] += red[t + off];
    __syncthreads();
  }
  if (t == 0) bc[j] = red[0] + bih[j];
}

// x packed per step-slice (KC=8): slice k holds x[:, :, 127+k] for k in [1,128)
__global__ void k_xprep(const float* __restrict__ x, u16* __restrict__ xhi,
                        u16* __restrict__ xlo) {
  __shared__ float t[64][129];
  int bid = blockIdx.x;
  int b = bid >> 2, d0 = (bid & 3) << 6;
  int tid = threadIdx.x;
#pragma unroll
  for (int i = 0; i < 32; ++i) {
    int idx = i * 256 + tid;
    int dd = idx >> 7, tt = idx & 127;
    t[dd][tt] = x[(size_t)b * 65536 + (size_t)(d0 + dd) * 256 + 128 + tt];
  }
  __syncthreads();
#pragma unroll
  for (int i = 0; i < 32; ++i) {
    int idx = i * 256 + tid;
    int dd = idx & 63, kk = idx >> 6;
    if (kk < 127) {
      float v = t[dd][kk];
      u16 hi = f2bf(v);
      size_t o = (size_t)(kk + 1) * 65536 + pidx(b, d0 + dd, 8);
      xhi[o] = hi;
      xlo[o] = f2bf(v - bf2f(hi));
    }
  }
}

// ---------- persistent recurrence: r15 structure + parallel flag barrier ----------
// 256 WGs x 512 thr. g=bid&7 (group/XCD), q=bid>>3 (e-superslice, 32 cols).
// WG: rows [g*32,+32), e-cols [q*32,+32), 3 planes + x-plane.
// W: cols [q*32,+16) LDS-resident; cols [+16,+32) streamed (reg-prefetched pre-spin).
// h: hi-only matmul via batched relaxed agent atomics.
// Barrier: per-WG epoch flags (64B-padded) — producer stores flag[g][q]=k+1
// (independent, no RMW chain); consumer wave-0 polls all 32 flags one-per-lane.
__launch_bounds__(512, 1)
__global__ void k_gru5(u16* __restrict__ hhi, u16* __restrict__ hlo,
                       const u16* __restrict__ xhi, const u16* __restrict__ xlo,
                       const u16* __restrict__ whp, const u16* __restrict__ wcp,
                       const float* __restrict__ bih, const float* __restrict__ bcb,
                       const float* __restrict__ bhh, u16* __restrict__ ys,
                       unsigned* __restrict__ bar) {
  __shared__ __align__(16) u16 lwh[3][32][512];  // 96KB  (eb16 = 2q)
  __shared__ __align__(16) u16 lwc[3][8][512];   // 24KB  (eb16 = 2q)
  __shared__ __align__(16) float red[2][8][256]; // 16KB  [mw][eb*4+gate][frag]
  __shared__ __align__(16) u16 sth[32][40];      // 2.5KB
  __shared__ __align__(16) u16 stl[32][40];      // 2.5KB
  __shared__ u16 hold_h[32][36];                 // 2.25KB
  __shared__ u16 hold_l[32][36];                 // 2.25KB

  int bid = blockIdx.x;
  int g = bid & 7, q = bid >> 3;
  int tid = threadIdx.x;
  int w = tid >> 6, lane = tid & 63, l15 = lane & 15, l4 = lane >> 4;
  int mw = w & 1, ks = w >> 1;  // mw: 16-row half, ks: 4-way K-split

  // LDS W: frags for rows 6q..6q+2 are contiguous (96 whh frags + 24 wc frags)
  {
    const u16* s1 = whp + (size_t)(6 * q) * 32 * 512;
    u16* d1 = &lwh[0][0][0];
#pragma unroll
    for (int i = 0; i < 12; ++i)
      *(uint4*)(d1 + i * 4096 + tid * 8) = *(const uint4*)(s1 + i * 4096 + tid * 8);
    const u16* s2 = wcp + (size_t)(6 * q) * 8 * 512;
    u16* d2 = &lwc[0][0][0];
#pragma unroll
    for (int i = 0; i < 3; ++i)
      *(uint4*)(d2 + i * 4096 + tid * 8) = *(const uint4*)(s2 + i * 4096 + tid * 8);
  }
  __syncthreads();

  // biases for both e-blocks this thread finalizes (only ks==0 uses them)
  float bAr[2], bAz[2], bAn[2], bBr[2], bBz[2], bBn[2], bhn_[2];
#pragma unroll
  for (int eb = 0; eb < 2; ++eb) {
    int e = q * 32 + eb * 16 + l15;
    float hr = bhh[e], hz = bhh[1024 + e];
    bhn_[eb] = bhh[2048 + e];
    bAr[eb] = bih[e] + hr;
    bAz[eb] = bih[1024 + e] + hz;
    bAn[eb] = bih[2048 + e];
    bBr[eb] = bcb[e] + hr;
    bBz[eb] = bcb[1024 + e] + hz;
    bBn[eb] = bcb[2048 + e];
  }

  // flag slots: 16 u32 (64B) apart; group g's 32 flags at bar + (g*32+q)*16
  unsigned* myflag = bar + (size_t)(g * 32 + q) * 16;
  const unsigned* pollflag = bar + (size_t)(g * 32 + (lane & 31)) * 16;

  int rg = g * 2 + mw;  // 16-row frag group for this wave's A operand
  // streamed W pointers (rows 6q+3..6q+5 = eb16 2q+1), plain cached / L2-resident
  const u16* Bs0 = whp + (size_t)(6 * q + 3) * 32 * 512 + (size_t)(lane * 8);
  const u16* Bs1 = whp + (size_t)(6 * q + 4) * 32 * 512 + (size_t)(lane * 8);
  const u16* Bs2 = whp + (size_t)(6 * q + 5) * 32 * 512 + (size_t)(lane * 8);
  const u16* Cs0 = wcp + (size_t)(6 * q + 3) * 8 * 512 + (size_t)(lane * 8);
  const u16* Cs1 = wcp + (size_t)(6 * q + 4) * 8 * 512 + (size_t)(lane * 8);
  const u16* Cs2 = wcp + (size_t)(6 * q + 5) * 8 * 512 + (size_t)(lane * 8);

  for (int k = 0; k < 128; ++k) {
    int cur = k & 1, nxt = cur ^ 1;

    f32x4 R0{}, Z0{}, N0{}, X0{}, R1{}, Z1{}, N1{}, X1{};

    // ---- prefetch this wave's streamed-W h-part frags into registers
    //      (plain loads, read-only data, no h dependency -> overlaps barrier wait)
    bf16x8 pb0[8], pb1[8], pb2[8];
#pragma unroll
    for (int c = 0; c < 8; ++c) {
      int kk = ks * 8 + c;
      pb0[c] = *(const bf16x8*)(Bs0 + (size_t)kk * 512);
      pb1[c] = *(const bf16x8*)(Bs1 + (size_t)kk * 512);
      pb2[c] = *(const bf16x8*)(Bs2 + (size_t)kk * 512);
    }

    // ---- x-part FIRST (no h dependency): overlaps barrier wait ----
    if (k > 0) {
      const u16* Xh = xhi + (size_t)k * 65536 + (size_t)rg * 4096 + (size_t)(lane * 8);
      const u16* Xl = xlo + (size_t)k * 65536 + (size_t)rg * 4096 + (size_t)(lane * 8);
#pragma unroll
      for (int c = 0; c < 2; ++c) {
        int kc = ks * 2 + c;
        bf16x8 ah = *(const bf16x8*)(Xh + (size_t)kc * 512);
        bf16x8 al = *(const bf16x8*)(Xl + (size_t)kc * 512);
        bf16x8 c00 = *(const bf16x8*)&lwc[0][kc][lane * 8];
        bf16x8 c10 = *(const bf16x8*)&lwc[1][kc][lane * 8];
        bf16x8 c20 = *(const bf16x8*)&lwc[2][kc][lane * 8];
        bf16x8 c01 = *(const bf16x8*)(Cs0 + (size_t)kc * 512);
        bf16x8 c11 = *(const bf16x8*)(Cs1 + (size_t)kc * 512);
        bf16x8 c21 = *(const bf16x8*)(Cs2 + (size_t)kc * 512);
        R0 = mfma16(ah, c00, R0); R0 = mfma16(al, c00, R0);
        Z0 = mfma16(ah, c10, Z0); Z0 = mfma16(al, c10, Z0);
        X0 = mfma16(ah, c20, X0); X0 = mfma16(al, c20, X0);
        R1 = mfma16(ah, c01, R1); R1 = mfma16(al, c01, R1);
        Z1 = mfma16(ah, c11, Z1); Z1 = mfma16(al, c11, Z1);
        X1 = mfma16(ah, c21, X1); X1 = mfma16(al, c21, X1);
      }
      // ---- group barrier wait: wave-0 polls all 32 flags, one per lane ----
      if (w == 0) {
        while (true) {
          unsigned v = __hip_atomic_load(pollflag, __ATOMIC_RELAXED,
                                         __HIP_MEMORY_SCOPE_AGENT);
          if (__all((int)(v >= (unsigned)k))) break;
          __builtin_amdgcn_s_sleep(2);
        }
      }
      __syncthreads();
    }

    // ---- batched coherent h loads (8 outstanding, one latency ramp) ----
    const u16* Hh = hhi + (size_t)cur * 262144 + (size_t)rg * 16384 + (size_t)(lane * 8);
    bf16x8 ahv[8];
#pragma unroll
    for (int c = 0; c < 8; ++c)
      ahv[c] = ld_coh8(Hh + (size_t)(ks * 8 + c) * 512);

    // ---- h-part: HI only; A = batched regs, B = LDS + prefetched regs ----
#pragma unroll
    for (int c = 0; c < 8; ++c) {
      int kk = ks * 8 + c;
      bf16x8 b00 = *(const bf16x8*)&lwh[0][kk][lane * 8];
      bf16x8 b10 = *(const bf16x8*)&lwh[1][kk][lane * 8];
      bf16x8 b20 = *(const bf16x8*)&lwh[2][kk][lane * 8];
      R0 = mfma16(ahv[c], b00, R0);
      Z0 = mfma16(ahv[c], b10, Z0);
      N0 = mfma16(ahv[c], b20, N0);
      R1 = mfma16(ahv[c], pb0[c], R1);
      Z1 = mfma16(ahv[c], pb1[c], Z1);
      N1 = mfma16(ahv[c], pb2[c], N1);
    }

    // ---- fold round 1: ks==3 writes red (+ hold stash) ----
    if (ks == 3) {
      size_t ho = (size_t)cur * 262144 + (size_t)(rg * 32 + q) * 512 + (size_t)(lane * 8);
      bf16x8 hh = ld_coh8(hhi + ho);
      bf16x8 hl = ld_coh8(hlo + ho);
      int r15 = lane & 15, oct = lane >> 4;
#pragma unroll
      for (int j = 0; j < 8; ++j) {
        hold_h[mw * 16 + r15][oct * 8 + j] = (u16)hh[j];
        hold_l[mw * 16 + r15][oct * 8 + j] = (u16)hl[j];
      }
      *(f32x4*)&red[mw][0][lane * 4] = R0;
      *(f32x4*)&red[mw][1][lane * 4] = Z0;
      *(f32x4*)&red[mw][2][lane * 4] = N0;
      *(f32x4*)&red[mw][3][lane * 4] = X0;
      *(f32x4*)&red[mw][4][lane * 4] = R1;
      *(f32x4*)&red[mw][5][lane * 4] = Z1;
      *(f32x4*)&red[mw][6][lane * 4] = N1;
      *(f32x4*)&red[mw][7][lane * 4] = X1;
    }
    __syncthreads();
    if (ks == 2) {
      *(f32x4*)&red[mw][0][lane * 4] = R0 + *(const f32x4*)&red[mw][0][lane * 4];
      *(f32x4*)&red[mw][1][lane * 4] = Z0 + *(const f32x4*)&red[mw][1][lane * 4];
      *(f32x4*)&red[mw][2][lane * 4] = N0 + *(const f32x4*)&red[mw][2][lane * 4];
      *(f32x4*)&red[mw][3][lane * 4] = X0 + *(const f32x4*)&red[mw][3][lane * 4];
      *(f32x4*)&red[mw][4][lane * 4] = R1 + *(const f32x4*)&red[mw][4][lane * 4];
      *(f32x4*)&red[mw][5][lane * 4] = Z1 + *(const f32x4*)&red[mw][5][lane * 4];
      *(f32x4*)&red[mw][6][lane * 4] = N1 + *(const f32x4*)&red[mw][6][lane * 4];
      *(f32x4*)&red[mw][7][lane * 4] = X1 + *(const f32x4*)&red[mw][7][lane * 4];
    }
    __syncthreads();
    if (ks == 1) {
      *(f32x4*)&red[mw][0][lane * 4] = R0 + *(const f32x4*)&red[mw][0][lane * 4];
      *(f32x4*)&red[mw][1][lane * 4] = Z0 + *(const f32x4*)&red[mw][1][lane * 4];
      *(f32x4*)&red[mw][2][lane * 4] = N0 + *(const f32x4*)&red[mw][2][lane * 4];
      *(f32x4*)&red[mw][3][lane * 4] = X0 + *(const f32x4*)&red[mw][3][lane * 4];
      *(f32x4*)&red[mw][4][lane * 4] = R1 + *(const f32x4*)&red[mw][4][lane * 4];
      *(f32x4*)&red[mw][5][lane * 4] = Z1 + *(const f32x4*)&red[mw][5][lane * 4];
      *(f32x4*)&red[mw][6][lane * 4] = N1 + *(const f32x4*)&red[mw][6][lane * 4];
      *(f32x4*)&red[mw][7][lane * 4] = X1 + *(const f32x4*)&red[mw][7][lane * 4];
    }
    __syncthreads();
    if (ks == 0) {
      f32x4 vR0 = R0 + *(const f32x4*)&red[mw][0][lane * 4];
      f32x4 vZ0 = Z0 + *(const f32x4*)&red[mw][1][lane * 4];
      f32x4 vN0 = N0 + *(const f32x4*)&red[mw][2][lane * 4];
      f32x4 vX0 = X0 + *(const f32x4*)&red[mw][3][lane * 4];
      f32x4 vR1 = R1 + *(const f32x4*)&red[mw][4][lane * 4];
      f32x4 vZ1 = Z1 + *(const f32x4*)&red[mw][5][lane * 4];
      f32x4 vN1 = N1 + *(const f32x4*)&red[mw][6][lane * 4];
      f32x4 vX1 = X1 + *(const f32x4*)&red[mw][7][lane * 4];
#pragma unroll
      for (int eb = 0; eb < 2; ++eb) {
        f32x4 vR = eb ? vR1 : vR0;
        f32x4 vZ = eb ? vZ1 : vZ0;
        f32x4 vN = eb ? vN1 : vN0;
        f32x4 vX = eb ? vX1 : vX0;
        float bir = k ? bBr[eb] : bAr[eb];
        float biz = k ? bBz[eb] : bAz[eb];
        float bin = k ? bBn[eb] : bAn[eb];
        int e64 = eb * 16 + l15;
#pragma unroll
        for (int j = 0; j < 4; ++j) {
          int row_rel = mw * 16 + l4 * 4 + j;
          float hold = bf2f(hold_h[row_rel][e64]) + bf2f(hold_l[row_rel][e64]);
          float gr = vR[j] + bir;
          float gz = vZ[j] + biz;
          float gh = vN[j] + bhn_[eb];
          float gx = vX[j] + bin;
          float r = 1.f / (1.f + __expf(-gr));
          float z = 1.f / (1.f + __expf(-gz));
          float n = 1.f - 2.f / (1.f + __expf(2.f * (gx + r * gh)));
          float h = (1.f - z) * n + z * hold;
          u16 hi = f2bf(h);
          sth[row_rel][e64] = hi;
          stl[row_rel][e64] = f2bf(h - bf2f(hi));
        }
      }
    }
    __syncthreads();

    // ---- stores: h = 2 full frags (rg*32+q) hi+lo (write-through), ys (plain) ----
    if (tid < 256) {
      int mws = (tid >> 6) & 1, isLo = tid >> 7, l = tid & 63;
      int r15 = l & 15, oct = l >> 4;
      size_t off = (size_t)((g * 2 + mws) * 32 + q) * 512 + (size_t)(l * 8);
      const u16* src = isLo ? &stl[mws * 16 + r15][oct * 8] : &sth[mws * 16 + r15][oct * 8];
      u16* dst = (isLo ? hlo : hhi) + (size_t)nxt * 262144;
      st_coh16(dst + off, *(const uint4*)src);
    } else if (tid < 384) {
      int cc = tid - 256;             // [0,128): 32 rows x 4 chunks
      int b_rel = cc >> 2, oct = cc & 3;
      size_t f = (size_t)((g * 32 + b_rel) * 8 + (k >> 4)) * 32 + (size_t)q;
      *(uint4*)(ys + f * 512 + (size_t)(((oct << 4) | (k & 15)) * 8)) =
          *(const uint4*)&sth[b_rel][oct * 8];
    }

    if (k < 127) {
      // drain stores (syncthreads waits vmcnt(0) before s_barrier), then publish flag
      __syncthreads();
      if (tid == 0)
        __hip_atomic_store(myflag, (unsigned)(k + 1), __ATOMIC_RELAXED,
                           __HIP_MEMORY_SCOPE_AGENT);
    }
  }
}

// ---------- untokenizer: packed frags, direct full-line float4 stores, no big LDS ----------
__launch_bounds__(256, 4)
__global__ void k_untok3(const u16* __restrict__ ysp, const u16* __restrict__ wunp,
                         const float* __restrict__ bun, float* __restrict__ out) {
  int bid = blockIdx.x;  // 1024 = 512 mtiles x 2 d-halves
  int mtile = bid >> 1, dh = bid & 1;
  int b = mtile >> 1, kk0 = (mtile & 1) << 6;
  int w = threadIdx.x >> 6, lane = threadIdx.x & 63, l15 = lane & 15, l4 = lane >> 4;
  int rg = mtile * 4 + w;
  const u16* A = ysp + (size_t)rg * 16384 + (size_t)(lane * 8);
  f32x4 acc[8] = {};
  float bv[8];
#pragma unroll
  for (int nt = 0; nt < 8; ++nt) bv[nt] = bun[dh * 128 + nt * 16 + l15];
#pragma unroll 4
  for (int kc = 0; kc < 32; ++kc) {
    bf16x8 a = *(const bf16x8*)(A + (size_t)kc * 512);
#pragma unroll
    for (int nt = 0; nt < 8; ++nt) {
      const u16* B = wunp + ((size_t)((dh * 8 + nt) * 32 + kc)) * 512 + (size_t)(lane * 8);
      acc[nt] = mfma16(a, *(const bf16x8*)B, acc[nt]);
    }
  }
#pragma unroll
  for (int nt = 0; nt < 8; ++nt) {
    float4 v = {acc[nt][0] + bv[nt], acc[nt][1] + bv[nt], acc[nt][2] + bv[nt],
                acc[nt][3] + bv[nt]};
    int d = dh * 128 + nt * 16 + l15;
    *(float4*)(out + (size_t)b * 32768 + (size_t)d * 128 + kk0 + w * 16 + l4 * 4) = v;
  }
}

// ---------- launch ----------
extern "C" void kernel_launch(void* const* d_in, const int* in_sizes, int n_in,
                              void* d_out, int out_size, void* d_ws, size_t ws_size,
                              hipStream_t stream) {
  const float* c_in = (const float*)d_in[0];
  const float* x_in = (const float*)d_in[2];
  const float* Wih  = (const float*)d_in[3];
  const float* Whh  = (const float*)d_in[4];
  const float* bih  = (const float*)d_in[5];
  const float* bhh  = (const float*)d_in[6];
  const float* Wtok = (const float*)d_in[7];
  const float* btok = (const float*)d_in[8];
  const float* Wun  = (const float*)d_in[9];
  const float* bun  = (const float*)d_in[10];
  float* out = (float*)d_out;
  char* ws = (char*)d_ws;

  const size_t OW_HH = 0;                     // u16 packed [6144 frags][512]
  const size_t OW_C  = 6291456;               // u16 packed [1536 frags][512]
  const size_t OW_UN = 7864320;               // u16 packed [512 frags][512]
  const size_t OBC   = 8388608;               // f32 [3072]
  const size_t OXHI  = 8400896;               // u16 [128][65536]
  const size_t OXLO  = 25178112;
  const size_t OHHI  = 41955328;              // u16 [2][262144]
  const size_t OHLO  = 43003904;
  const size_t OYS   = 44052480;              // u16 packed [65536 frags][512]
  const size_t OBAR  = 111161344;             // u32 [4096] padded epoch flags (16KB)
  const size_t NEED  = 111177728;
  if (ws_size < NEED) return;

  u16* whh_p = (u16*)(ws + OW_HH);
  u16* wc_p  = (u16*)(ws + OW_C);
  u16* wun_p = (u16*)(ws + OW_UN);
  float* bc  = (float*)(ws + OBC);
  u16* xhi   = (u16*)(ws + OXHI);
  u16* xlo   = (u16*)(ws + OXLO);
  u16* hhi   = (u16*)(ws + OHHI);
  u16* hlo   = (u16*)(ws + OHLO);
  u16* ys    = (u16*)(ws + OYS);
  unsigned* bar = (unsigned*)(ws + OBAR);

  k_round<<<1024, 256, 0, stream>>>(Whh, Wun, whh_p, wun_p);
  k_wcomb<<<dim3(48, 4), 256, 0, stream>>>(Wih, Wtok, wc_p);
  k_bcomb<<<3072, 256, 0, stream>>>(Wih, btok, bih, bc);
  k_xprep<<<1024, 256, 0, stream>>>(x_in, xhi, xlo);
  k_hinit<<<1024, 256, 0, stream>>>(c_in, hhi, hlo);
  k_zero<<<16, 256, 0, stream>>>(bar);

  {
    u16* hhi_l = hhi;
    u16* hlo_l = hlo;
    const u16* xhi_l = xhi;
    const u16* xlo_l = xlo;
    const u16* whp_l = whh_p;
    const u16* wcp_l = wc_p;
    const float* bih_l = bih;
    const float* bc_l = bc;
    const float* bhh_l = bhh;
    u16* ys_l = ys;
    unsigned* bar_l = bar;
    void* args[] = {&hhi_l, &hlo_l, &xhi_l, &xlo_l, &whp_l, &wcp_l,
                    &bih_l, &bc_l, &bhh_l, &ys_l, &bar_l};
    hipLaunchCooperativeKernel((const void*)k_gru5, dim3(256), dim3(512), args, 0, stream);
  }

  k_untok3<<<1024, 256, 0, stream>>>(ys, wun_p, bun, out);
}

// Round 17
// 820.326 us; speedup vs baseline: 2.2035x; 1.1043x over previous
//
#include <hip/hip_runtime.h>
#include <cstdint>

typedef __attribute__((ext_vector_type(8))) short bf16x8;
typedef __attribute__((ext_vector_type(4))) float f32x4;
typedef unsigned short u16;
typedef unsigned long long u64;

// ---------- bf16 helpers (round-to-nearest-even) ----------
__device__ __forceinline__ u16 f2bf(float x) {
  unsigned u = __builtin_bit_cast(unsigned, x);
  return (u16)((u + 0x7FFFu + ((u >> 16) & 1u)) >> 16);
}
__device__ __forceinline__ float bf2f(u16 h) {
  unsigned u = ((unsigned)h) << 16;
  return __builtin_bit_cast(float, u);
}
__device__ __forceinline__ f32x4 mfma16(bf16x8 a, bf16x8 b, f32x4 c) {
  return __builtin_amdgcn_mfma_f32_16x16x32_bf16(a, b, c, 0, 0, 0);
}
__device__ __forceinline__ bf16x8 bc8(uint4 v) { return __builtin_bit_cast(bf16x8, v); }

// sc0 load: bypass L1, read from the XCD's L2 (intra-XCD producer/consumer exchange).
__device__ __forceinline__ void ld_sc0(const u16* p, uint4& v) {
  asm volatile("global_load_dwordx4 %0, %1, off sc0" : "=v"(v) : "v"(p));
}

// Packed MFMA-fragment index for Mat[r][k]: frag=(r>>4)*KC+(k>>5), lane=((k&31)>>3)<<4|(r&15), j=k&7
__device__ __forceinline__ size_t pidx(int r, int k, int KC) {
  return ((size_t)((r >> 4) * KC + (k >> 5))) * 512 +
         (size_t)(((((k & 31) >> 3) << 4) | (r & 15)) * 8) + (size_t)(k & 7);
}
// plane-triple interleaved gate row: orig (p, e) -> ((e>>4)*3+p)*16 + (e&15)
__device__ __forceinline__ int rowperm(int p, int e) {
  return (((e >> 4) * 3 + p) << 4) + (e & 15);
}

// ---------- setup kernels ----------
__global__ void k_round(const float* __restrict__ whh, const float* __restrict__ wun,
                        u16* __restrict__ whhp, u16* __restrict__ wunp) {
  int i = blockIdx.x * 256 + threadIdx.x, st = 1024 * 256;
  for (int j = i; j < 3072 * 1024; j += st) {
    int r = j >> 10, k = j & 1023;
    int p = r >> 10, e = r & 1023;
    whhp[pidx(rowperm(p, e), k, 32)] = f2bf(whh[j]);
  }
  for (int j = i; j < 256 * 1024; j += st) {
    int r = j >> 10, k = j & 1023;
    wunp[pidx(r, k, 32)] = f2bf(wun[j]);
  }
}

__global__ void k_hinit(const float* __restrict__ c, u16* __restrict__ hhi,
                        u16* __restrict__ hlo) {
  int i = blockIdx.x * 256 + threadIdx.x;  // 262144
  int b = i >> 10, e = i & 1023;
  float v = c[i];
  u16 hi = f2bf(v);
  size_t o = pidx(b, e, 32);
  hhi[o] = hi;
  hlo[o] = f2bf(v - bf2f(hi));
}

__global__ void k_zero(unsigned* __restrict__ bar) {
  bar[blockIdx.x * 256 + threadIdx.x] = 0u;  // 17*256 = 4352 words (flags + claim)
}

// W_comb = W_ih @ W_tok -> packed bf16 frags (KC=8), plane-interleaved rows
__global__ void k_wcomb(const float* __restrict__ wih, const float* __restrict__ wtok,
                        u16* __restrict__ wcb) {
  __shared__ float la[64][33];
  __shared__ float lb[32][65];
  int i0 = blockIdx.x << 6, j0 = blockIdx.y << 6;
  int tid = threadIdx.x;
  int ty = tid >> 4, tx = tid & 15;
  float acc[4][4] = {};
  for (int k0 = 0; k0 < 1024; k0 += 32) {
    __syncthreads();
#pragma unroll
    for (int i = 0; i < 8; ++i) {
      int r = (tid >> 5) + i * 8, cc = tid & 31;
      la[r][cc] = wih[(size_t)(i0 + r) * 1024 + k0 + cc];
    }
#pragma unroll
    for (int i = 0; i < 8; ++i) {
      int idx = i * 256 + tid;
      int r = idx >> 6, cc = idx & 63;
      lb[r][cc] = wtok[(size_t)(k0 + r) * 256 + j0 + cc];
    }
    __syncthreads();
#pragma unroll
    for (int kk = 0; kk < 32; ++kk) {
      float av[4], bv[4];
#pragma unroll
      for (int ii = 0; ii < 4; ++ii) av[ii] = la[ty * 4 + ii][kk];
#pragma unroll
      for (int jj = 0; jj < 4; ++jj) bv[jj] = lb[kk][tx * 4 + jj];
#pragma unroll
      for (int ii = 0; ii < 4; ++ii)
#pragma unroll
        for (int jj = 0; jj < 4; ++jj) acc[ii][jj] += av[ii] * bv[jj];
    }
  }
#pragma unroll
  for (int ii = 0; ii < 4; ++ii)
#pragma unroll
    for (int jj = 0; jj < 4; ++jj) {
      int r = i0 + ty * 4 + ii;
      int p = r >> 10, e = r & 1023;
      wcb[pidx(rowperm(p, e), j0 + tx * 4 + jj, 8)] = f2bf(acc[ii][jj]);
    }
}

__global__ void k_bcomb(const float* __restrict__ wih, const float* __restrict__ btok,
                        const float* __restrict__ bih, float* __restrict__ bc) {
  __shared__ float red[256];
  int j = blockIdx.x, t = threadIdx.x;
  float s = 0.f;
  for (int e = t; e < 1024; e += 256) s += wih[(size_t)j * 1024 + e] * btok[e];
  red[t] = s;
  __syncthreads();
  for (int off = 128; off > 0; off >>= 1) {
    if (t < off) red[t] += red[t + off];
    __syncthreads();
  }
  if (t == 0) bc[j] = red[0] + bih[j];
}

// x packed per step-slice (KC=8): slice k holds x[:, :, 127+k] for k in [1,128)
__global__ void k_xprep(const float* __restrict__ x, u16* __restrict__ xhi,
                        u16* __restrict__ xlo) {
  __shared__ float t[64][129];
  int bid = blockIdx.x;
  int b = bid >> 2, d0 = (bid & 3) << 6;
  int tid = threadIdx.x;
#pragma unroll
  for (int i = 0; i < 32; ++i) {
    int idx = i * 256 + tid;
    int dd = idx >> 7, tt = idx & 127;
    t[dd][tt] = x[(size_t)b * 65536 + (size_t)(d0 + dd) * 256 + 128 + tt];
  }
  __syncthreads();
#pragma unroll
  for (int i = 0; i < 32; ++i) {
    int idx = i * 256 + tid;
    int dd = idx & 63, kk = idx >> 6;
    if (kk < 127) {
      float v = t[dd][kk];
      u16 hi = f2bf(v);
      size_t o = (size_t)(kk + 1) * 65536 + pidx(b, d0 + dd, 8);
      xhi[o] = hi;
      xlo[o] = f2bf(v - bf2f(hi));
    }
  }
}

// ---------- persistent recurrence: XCC-claimed groups + intra-XCD L2 h exchange ----------
// 256 WGs x 512 thr. Each WG reads its physical XCD id (HW_REG_XCC_ID) and claims a
// slot q in that XCD's group -> co-location GUARANTEED (1 WG/CU forced by 148KB LDS,
// cooperative launch => 32 WGs per XCD). Group g: rows [g*32,+32), WG q: e-cols [q*32,+32).
// h exchange: PLAIN stores (write-through L1 -> update local L2) + sc0 LOADS (bypass
// L1, read local L2). No agent atomics on the h path. Flags stay agent-scope (r16).
__launch_bounds__(512, 1)
__global__ void k_gru5(u16* __restrict__ hhi, u16* __restrict__ hlo,
                       const u16* __restrict__ xhi, const u16* __restrict__ xlo,
                       const u16* __restrict__ whp, const u16* __restrict__ wcp,
                       const float* __restrict__ bih, const float* __restrict__ bcb,
                       const float* __restrict__ bhh, u16* __restrict__ ys,
                       unsigned* __restrict__ bar) {
  __shared__ __align__(16) u16 lwh[3][32][512];  // 96KB
  __shared__ __align__(16) u16 lwc[3][8][512];   // 24KB
  __shared__ __align__(16) float red[2][8][256]; // 16KB
  __shared__ __align__(16) u16 sth[32][40];      // 2.5KB
  __shared__ __align__(16) u16 stl[32][40];      // 2.5KB
  __shared__ u16 hold_h[32][36];                 // 2.25KB
  __shared__ u16 hold_l[32][36];                 // 2.25KB
  __shared__ int s_gq[2];

  int tid = threadIdx.x;
  // ---- dynamic group claim: g = physical XCD, q = claimed slot in that XCD ----
  if (tid == 0) {
    unsigned xcc;
    asm volatile("s_getreg_b32 %0, hwreg(HW_REG_XCC_ID)" : "=s"(xcc));
    xcc &= 7u;
    unsigned slot = __hip_atomic_fetch_add(bar + 4096 + xcc, 1u, __ATOMIC_RELAXED,
                                           __HIP_MEMORY_SCOPE_AGENT);
    s_gq[0] = (int)xcc;
    s_gq[1] = (int)(slot & 31u);
  }
  __syncthreads();
  int g = s_gq[0], q = s_gq[1];

  int w = tid >> 6, lane = tid & 63, l15 = lane & 15, l4 = lane >> 4;
  int mw = w & 1, ks = w >> 1;  // mw: 16-row half, ks: 4-way K-split

  // LDS W: frags for rows 6q..6q+2 are contiguous (96 whh frags + 24 wc frags)
  {
    const u16* s1 = whp + (size_t)(6 * q) * 32 * 512;
    u16* d1 = &lwh[0][0][0];
#pragma unroll
    for (int i = 0; i < 12; ++i)
      *(uint4*)(d1 + i * 4096 + tid * 8) = *(const uint4*)(s1 + i * 4096 + tid * 8);
    const u16* s2 = wcp + (size_t)(6 * q) * 8 * 512;
    u16* d2 = &lwc[0][0][0];
#pragma unroll
    for (int i = 0; i < 3; ++i)
      *(uint4*)(d2 + i * 4096 + tid * 8) = *(const uint4*)(s2 + i * 4096 + tid * 8);
  }
  __syncthreads();

  // biases for both e-blocks this thread finalizes (only ks==0 uses them)
  float bAr[2], bAz[2], bAn[2], bBr[2], bBz[2], bBn[2], bhn_[2];
#pragma unroll
  for (int eb = 0; eb < 2; ++eb) {
    int e = q * 32 + eb * 16 + l15;
    float hr = bhh[e], hz = bhh[1024 + e];
    bhn_[eb] = bhh[2048 + e];
    bAr[eb] = bih[e] + hr;
    bAz[eb] = bih[1024 + e] + hz;
    bAn[eb] = bih[2048 + e];
    bBr[eb] = bcb[e] + hr;
    bBz[eb] = bcb[1024 + e] + hz;
    bBn[eb] = bcb[2048 + e];
  }

  // flag slots: 16 u32 (64B) apart; group g's 32 flags at bar + (g*32+q)*16
  unsigned* myflag = bar + (size_t)(g * 32 + q) * 16;
  const unsigned* pollflag = bar + (size_t)(g * 32 + (lane & 31)) * 16;

  int rg = g * 2 + mw;  // 16-row frag group for this wave's A operand
  // streamed W pointers (rows 6q+3..6q+5), plain cached / L2-resident
  const u16* Bs0 = whp + (size_t)(6 * q + 3) * 32 * 512 + (size_t)(lane * 8);
  const u16* Bs1 = whp + (size_t)(6 * q + 4) * 32 * 512 + (size_t)(lane * 8);
  const u16* Bs2 = whp + (size_t)(6 * q + 5) * 32 * 512 + (size_t)(lane * 8);
  const u16* Cs0 = wcp + (size_t)(6 * q + 3) * 8 * 512 + (size_t)(lane * 8);
  const u16* Cs1 = wcp + (size_t)(6 * q + 4) * 8 * 512 + (size_t)(lane * 8);
  const u16* Cs2 = wcp + (size_t)(6 * q + 5) * 8 * 512 + (size_t)(lane * 8);

  for (int k = 0; k < 128; ++k) {
    int cur = k & 1, nxt = cur ^ 1;

    f32x4 R0{}, Z0{}, N0{}, X0{}, R1{}, Z1{}, N1{}, X1{};

    // ---- prefetch this wave's streamed-W h-part frags into registers
    bf16x8 pb0[8], pb1[8], pb2[8];
#pragma unroll
    for (int c = 0; c < 8; ++c) {
      int kk = ks * 8 + c;
      pb0[c] = *(const bf16x8*)(Bs0 + (size_t)kk * 512);
      pb1[c] = *(const bf16x8*)(Bs1 + (size_t)kk * 512);
      pb2[c] = *(const bf16x8*)(Bs2 + (size_t)kk * 512);
    }

    // ---- x-part FIRST (no h dependency): overlaps barrier wait ----
    if (k > 0) {
      const u16* Xh = xhi + (size_t)k * 65536 + (size_t)rg * 4096 + (size_t)(lane * 8);
      const u16* Xl = xlo + (size_t)k * 65536 + (size_t)rg * 4096 + (size_t)(lane * 8);
#pragma unroll
      for (int c = 0; c < 2; ++c) {
        int kc = ks * 2 + c;
        bf16x8 ah = *(const bf16x8*)(Xh + (size_t)kc * 512);
        bf16x8 al = *(const bf16x8*)(Xl + (size_t)kc * 512);
        bf16x8 c00 = *(const bf16x8*)&lwc[0][kc][lane * 8];
        bf16x8 c10 = *(const bf16x8*)&lwc[1][kc][lane * 8];
        bf16x8 c20 = *(const bf16x8*)&lwc[2][kc][lane * 8];
        bf16x8 c01 = *(const bf16x8*)(Cs0 + (size_t)kc * 512);
        bf16x8 c11 = *(const bf16x8*)(Cs1 + (size_t)kc * 512);
        bf16x8 c21 = *(const bf16x8*)(Cs2 + (size_t)kc * 512);
        R0 = mfma16(ah, c00, R0); R0 = mfma16(al, c00, R0);
        Z0 = mfma16(ah, c10, Z0); Z0 = mfma16(al, c10, Z0);
        X0 = mfma16(ah, c20, X0); X0 = mfma16(al, c20, X0);
        R1 = mfma16(ah, c01, R1); R1 = mfma16(al, c01, R1);
        Z1 = mfma16(ah, c11, Z1); Z1 = mfma16(al, c11, Z1);
        X1 = mfma16(ah, c21, X1); X1 = mfma16(al, c21, X1);
      }
      // ---- group barrier wait: wave-0 polls all 32 flags (agent, validated r16) ----
      if (w == 0) {
        while (true) {
          unsigned v = __hip_atomic_load(pollflag, __ATOMIC_RELAXED,
                                         __HIP_MEMORY_SCOPE_AGENT);
          if (__all((int)(v >= (unsigned)k))) break;
          __builtin_amdgcn_s_sleep(2);
        }
      }
      __syncthreads();
    }

    // ---- batched sc0 h loads from the XCD's L2 (hi-only matmul A) ----
    const u16* Hh = hhi + (size_t)cur * 262144 + (size_t)rg * 16384 + (size_t)(lane * 8);
    uint4 ahr[8];
    uint4 hhr{}, hlr{};
    __builtin_amdgcn_sched_barrier(0);
#pragma unroll
    for (int c = 0; c < 8; ++c)
      ld_sc0(Hh + (size_t)(ks * 8 + c) * 512, ahr[c]);
    if (ks == 3) {
      size_t ho = (size_t)cur * 262144 + (size_t)(rg * 32 + q) * 512 + (size_t)(lane * 8);
      ld_sc0(hhi + ho, hhr);
      ld_sc0(hlo + ho, hlr);
    }
    asm volatile("s_waitcnt vmcnt(0)" ::: "memory");
    __builtin_amdgcn_sched_barrier(0);

    // ---- h-part: HI only; A = sc0 regs, B = LDS + prefetched regs ----
#pragma unroll
    for (int c = 0; c < 8; ++c) {
      int kk = ks * 8 + c;
      bf16x8 a = bc8(ahr[c]);
      bf16x8 b00 = *(const bf16x8*)&lwh[0][kk][lane * 8];
      bf16x8 b10 = *(const bf16x8*)&lwh[1][kk][lane * 8];
      bf16x8 b20 = *(const bf16x8*)&lwh[2][kk][lane * 8];
      R0 = mfma16(a, b00, R0);
      Z0 = mfma16(a, b10, Z0);
      N0 = mfma16(a, b20, N0);
      R1 = mfma16(a, pb0[c], R1);
      Z1 = mfma16(a, pb1[c], Z1);
      N1 = mfma16(a, pb2[c], N1);
    }

    // ---- fold round 1: ks==3 writes red (+ hold stash) ----
    if (ks == 3) {
      bf16x8 hh = bc8(hhr), hl = bc8(hlr);
      int r15 = lane & 15, oct = lane >> 4;
#pragma unroll
      for (int j = 0; j < 8; ++j) {
        hold_h[mw * 16 + r15][oct * 8 + j] = (u16)hh[j];
        hold_l[mw * 16 + r15][oct * 8 + j] = (u16)hl[j];
      }
      *(f32x4*)&red[mw][0][lane * 4] = R0;
      *(f32x4*)&red[mw][1][lane * 4] = Z0;
      *(f32x4*)&red[mw][2][lane * 4] = N0;
      *(f32x4*)&red[mw][3][lane * 4] = X0;
      *(f32x4*)&red[mw][4][lane * 4] = R1;
      *(f32x4*)&red[mw][5][lane * 4] = Z1;
      *(f32x4*)&red[mw][6][lane * 4] = N1;
      *(f32x4*)&red[mw][7][lane * 4] = X1;
    }
    __syncthreads();
    if (ks == 2) {
      *(f32x4*)&red[mw][0][lane * 4] = R0 + *(const f32x4*)&red[mw][0][lane * 4];
      *(f32x4*)&red[mw][1][lane * 4] = Z0 + *(const f32x4*)&red[mw][1][lane * 4];
      *(f32x4*)&red[mw][2][lane * 4] = N0 + *(const f32x4*)&red[mw][2][lane * 4];
      *(f32x4*)&red[mw][3][lane * 4] = X0 + *(const f32x4*)&red[mw][3][lane * 4];
      *(f32x4*)&red[mw][4][lane * 4] = R1 + *(const f32x4*)&red[mw][4][lane * 4];
      *(f32x4*)&red[mw][5][lane * 4] = Z1 + *(const f32x4*)&red[mw][5][lane * 4];
      *(f32x4*)&red[mw][6][lane * 4] = N1 + *(const f32x4*)&red[mw][6][lane * 4];
      *(f32x4*)&red[mw][7][lane * 4] = X1 + *(const f32x4*)&red[mw][7][lane * 4];
    }
    __syncthreads();
    if (ks == 1) {
      *(f32x4*)&red[mw][0][lane * 4] = R0 + *(const f32x4*)&red[mw][0][lane * 4];
      *(f32x4*)&red[mw][1][lane * 4] = Z0 + *(const f32x4*)&red[mw][1][lane * 4];
      *(f32x4*)&red[mw][2][lane * 4] = N0 + *(const f32x4*)&red[mw][2][lane * 4];
      *(f32x4*)&red[mw][3][lane * 4] = X0 + *(const f32x4*)&red[mw][3][lane * 4];
      *(f32x4*)&red[mw][4][lane * 4] = R1 + *(const f32x4*)&red[mw][4][lane * 4];
      *(f32x4*)&red[mw][5][lane * 4] = Z1 + *(const f32x4*)&red[mw][5][lane * 4];
      *(f32x4*)&red[mw][6][lane * 4] = N1 + *(const f32x4*)&red[mw][6][lane * 4];
      *(f32x4*)&red[mw][7][lane * 4] = X1 + *(const f32x4*)&red[mw][7][lane * 4];
    }
    __syncthreads();
    if (ks == 0) {
      f32x4 vR0 = R0 + *(const f32x4*)&red[mw][0][lane * 4];
      f32x4 vZ0 = Z0 + *(const f32x4*)&red[mw][1][lane * 4];
      f32x4 vN0 = N0 + *(const f32x4*)&red[mw][2][lane * 4];
      f32x4 vX0 = X0 + *(const f32x4*)&red[mw][3][lane * 4];
      f32x4 vR1 = R1 + *(const f32x4*)&red[mw][4][lane * 4];
      f32x4 vZ1 = Z1 + *(const f32x4*)&red[mw][5][lane * 4];
      f32x4 vN1 = N1 + *(const f32x4*)&red[mw][6][lane * 4];
      f32x4 vX1 = X1 + *(const f32x4*)&red[mw][7][lane * 4];
#pragma unroll
      for (int eb = 0; eb < 2; ++eb) {
        f32x4 vR = eb ? vR1 : vR0;
        f32x4 vZ = eb ? vZ1 : vZ0;
        f32x4 vN = eb ? vN1 : vN0;
        f32x4 vX = eb ? vX1 : vX0;
        float bir = k ? bBr[eb] : bAr[eb];
        float biz = k ? bBz[eb] : bAz[eb];
        float bin = k ? bBn[eb] : bAn[eb];
        int e64 = eb * 16 + l15;
#pragma unroll
        for (int j = 0; j < 4; ++j) {
          int row_rel = mw * 16 + l4 * 4 + j;
          float hold = bf2f(hold_h[row_rel][e64]) + bf2f(hold_l[row_rel][e64]);
          float gr = vR[j] + bir;
          float gz = vZ[j] + biz;
          float gh = vN[j] + bhn_[eb];
          float gx = vX[j] + bin;
          float r = 1.f / (1.f + __expf(-gr));
          float z = 1.f / (1.f + __expf(-gz));
          float n = 1.f - 2.f / (1.f + __expf(2.f * (gx + r * gh)));
          float h = (1.f - z) * n + z * hold;
          u16 hi = f2bf(h);
          sth[row_rel][e64] = hi;
          stl[row_rel][e64] = f2bf(h - bf2f(hi));
        }
      }
    }
    __syncthreads();

    // ---- stores: h = 2 full frags hi+lo, PLAIN (update local L2); ys plain ----
    if (tid < 256) {
      int mws = (tid >> 6) & 1, isLo = tid >> 7, l = tid & 63;
      int r15 = l & 15, oct = l >> 4;
      size_t off = (size_t)((g * 2 + mws) * 32 + q) * 512 + (size_t)(l * 8);
      const u16* src = isLo ? &stl[mws * 16 + r15][oct * 8] : &sth[mws * 16 + r15][oct * 8];
      u16* dst = (isLo ? hlo : hhi) + (size_t)nxt * 262144;
      *(uint4*)(dst + off) = *(const uint4*)src;
    } else if (tid < 384) {
      int cc = tid - 256;             // [0,128): 32 rows x 4 chunks
      int b_rel = cc >> 2, oct = cc & 3;
      size_t f = (size_t)((g * 32 + b_rel) * 8 + (k >> 4)) * 32 + (size_t)q;
      *(uint4*)(ys + f * 512 + (size_t)(((oct << 4) | (k & 15)) * 8)) =
          *(const uint4*)&sth[b_rel][oct * 8];
    }

    if (k < 127) {
      // drain stores (syncthreads waits vmcnt(0) before s_barrier), then publish flag
      __syncthreads();
      if (tid == 0)
        __hip_atomic_store(myflag, (unsigned)(k + 1), __ATOMIC_RELAXED,
                           __HIP_MEMORY_SCOPE_AGENT);
    }
  }
}

// ---------- untokenizer: packed frags, direct full-line float4 stores, no big LDS ----------
__launch_bounds__(256, 4)
__global__ void k_untok3(const u16* __restrict__ ysp, const u16* __restrict__ wunp,
                         const float* __restrict__ bun, float* __restrict__ out) {
  int bid = blockIdx.x;  // 1024 = 512 mtiles x 2 d-halves
  int mtile = bid >> 1, dh = bid & 1;
  int b = mtile >> 1, kk0 = (mtile & 1) << 6;
  int w = threadIdx.x >> 6, lane = threadIdx.x & 63, l15 = lane & 15, l4 = lane >> 4;
  int rg = mtile * 4 + w;
  const u16* A = ysp + (size_t)rg * 16384 + (size_t)(lane * 8);
  f32x4 acc[8] = {};
  float bv[8];
#pragma unroll
  for (int nt = 0; nt < 8; ++nt) bv[nt] = bun[dh * 128 + nt * 16 + l15];
#pragma unroll 4
  for (int kc = 0; kc < 32; ++kc) {
    bf16x8 a = *(const bf16x8*)(A + (size_t)kc * 512);
#pragma unroll
    for (int nt = 0; nt < 8; ++nt) {
      const u16* B = wunp + ((size_t)((dh * 8 + nt) * 32 + kc)) * 512 + (size_t)(lane * 8);
      acc[nt] = mfma16(a, *(const bf16x8*)B, acc[nt]);
    }
  }
#pragma unroll
  for (int nt = 0; nt < 8; ++nt) {
    float4 v = {acc[nt][0] + bv[nt], acc[nt][1] + bv[nt], acc[nt][2] + bv[nt],
                acc[nt][3] + bv[nt]};
    int d = dh * 128 + nt * 16 + l15;
    *(float4*)(out + (size_t)b * 32768 + (size_t)d * 128 + kk0 + w * 16 + l4 * 4) = v;
  }
}

// ---------- launch ----------
extern "C" void kernel_launch(void* const* d_in, const int* in_sizes, int n_in,
                              void* d_out, int out_size, void* d_ws, size_t ws_size,
                              hipStream_t stream) {
  const float* c_in = (const float*)d_in[0];
  const float* x_in = (const float*)d_in[2];
  const float* Wih  = (const float*)d_in[3];
  const float* Whh  = (const float*)d_in[4];
  const float* bih  = (const float*)d_in[5];
  const float* bhh  = (const float*)d_in[6];
  const float* Wtok = (const float*)d_in[7];
  const float* btok = (const float*)d_in[8];
  const float* Wun  = (const float*)d_in[9];
  const float* bun  = (const float*)d_in[10];
  float* out = (float*)d_out;
  char* ws = (char*)d_ws;

  const size_t OW_HH = 0;                     // u16 packed [6144 frags][512]
  const size_t OW_C  = 6291456;               // u16 packed [1536 frags][512]
  const size_t OW_UN = 7864320;               // u16 packed [512 frags][512]
  const size_t OBC   = 8388608;               // f32 [3072]
  const size_t OXHI  = 8400896;               // u16 [128][65536]
  const size_t OXLO  = 25178112;
  const size_t OHHI  = 41955328;              // u16 [2][262144]
  const size_t OHLO  = 43003904;
  const size_t OYS   = 44052480;              // u16 packed [65536 frags][512]
  const size_t OBAR  = 111161344;             // u32 [4096] flags + u32[8] claim (17408 B)
  const size_t NEED  = 111178752;
  if (ws_size < NEED) return;

  u16* whh_p = (u16*)(ws + OW_HH);
  u16* wc_p  = (u16*)(ws + OW_C);
  u16* wun_p = (u16*)(ws + OW_UN);
  float* bc  = (float*)(ws + OBC);
  u16* xhi   = (u16*)(ws + OXHI);
  u16* xlo   = (u16*)(ws + OXLO);
  u16* hhi   = (u16*)(ws + OHHI);
  u16* hlo   = (u16*)(ws + OHLO);
  u16* ys    = (u16*)(ws + OYS);
  unsigned* bar = (unsigned*)(ws + OBAR);

  k_round<<<1024, 256, 0, stream>>>(Whh, Wun, whh_p, wun_p);
  k_wcomb<<<dim3(48, 4), 256, 0, stream>>>(Wih, Wtok, wc_p);
  k_bcomb<<<3072, 256, 0, stream>>>(Wih, btok, bih, bc);
  k_xprep<<<1024, 256, 0, stream>>>(x_in, xhi, xlo);
  k_hinit<<<1024, 256, 0, stream>>>(c_in, hhi, hlo);
  k_zero<<<17, 256, 0, stream>>>(bar);

  {
    u16* hhi_l = hhi;
    u16* hlo_l = hlo;
    const u16* xhi_l = xhi;
    const u16* xlo_l = xlo;
    const u16* whp_l = whh_p;
    const u16* wcp_l = wc_p;
    const float* bih_l = bih;
    const float* bc_l = bc;
    const float* bhh_l = bhh;
    u16* ys_l = ys;
    unsigned* bar_l = bar;
    void* args[] = {&hhi_l, &hlo_l, &xhi_l, &xlo_l, &whp_l, &wcp_l,
                    &bih_l, &bc_l, &bhh_l, &ys_l, &bar_l};
    hipLaunchCooperativeKernel((const void*)k_gru5, dim3(256), dim3(512), args, 0, stream);
  }

  k_untok3<<<1024, 256, 0, stream>>>(ys, wun_p, bun, out);
}